// Round 2
// baseline (883.353 us; speedup 1.0000x reference)
//
#include <hip/hip_runtime.h>

typedef short short8 __attribute__((ext_vector_type(8)));
typedef float f32x4 __attribute__((ext_vector_type(4)));
typedef unsigned short ushort_t;

__device__ __forceinline__ unsigned short f2bf(float f){
  unsigned int u = __builtin_bit_cast(unsigned int, f);
  u += 0x7FFFu + ((u >> 16) & 1u);
  return (unsigned short)(u >> 16);
}

// ---------------- elementwise casts ----------------
__global__ __launch_bounds__(256) void cast_bf16_kernel(const float* __restrict__ in,
                                                        ushort_t* __restrict__ out, long n4){
  long i = (long)blockIdx.x*256 + threadIdx.x;
  if (i >= n4) return;
  const float4 v = reinterpret_cast<const float4*>(in)[i];
  ushort4 o; o.x=f2bf(v.x); o.y=f2bf(v.y); o.z=f2bf(v.z); o.w=f2bf(v.w);
  reinterpret_cast<ushort4*>(out)[i] = o;
}

// ---------------- RoPE (+ optional 1/sqrt(Dh) fold) ----------------
// X: (B,S,DIM) f32 -> Out bf16 same layout. pairs (d, d+64) within each head.
__global__ __launch_bounds__(256) void rope_kernel(const float* __restrict__ X,
                                                   const float* __restrict__ cosb,
                                                   const float* __restrict__ sinb,
                                                   ushort_t* __restrict__ Out, float scale){
  long idx = (long)blockIdx.x*256 + threadIdx.x;   // B*S*H*64 threads
  int d = idx & 63;
  long rest = idx >> 6;
  int h = rest & 15; rest >>= 4;
  int s = rest & 2047;
  int b = (int)(rest >> 11);
  long base = ((long)(b*2048 + s))*2048 + h*128;
  float x1 = X[base + d], x2 = X[base + 64 + d];
  float cc = cosb[s*64 + d], ss = sinb[s*64 + d];
  Out[base + d]      = f2bf((x1*cc - x2*ss)*scale);
  Out[base + 64 + d] = f2bf((x1*ss + x2*cc)*scale);
}

// ---------------- V cast + transpose to (B*H, Dh, S) ----------------
// grid: (S/64, B*H), block 256
__global__ __launch_bounds__(256) void vt_kernel(const float* __restrict__ vf,
                                                 ushort_t* __restrict__ vt){
  const int s0 = blockIdx.x*64;
  const int bh = blockIdx.y;            // b*16 + h
  const int b = bh >> 4, h = bh & 15;
  __shared__ ushort_t tile[128][66];    // [d][s], padded
  for (int it = 0; it < 32; ++it){
    int idx = it*256 + threadIdx.x;     // 8192 elements
    int sl = idx >> 7, d = idx & 127;
    float v = vf[((long)(b*2048 + s0 + sl))*2048 + h*128 + d];
    tile[d][sl] = f2bf(v);
  }
  __syncthreads();
  for (int it = 0; it < 32; ++it){
    int idx = it*256 + threadIdx.x;
    int d = idx >> 6, sl = idx & 63;
    vt[((long)(bh*128 + d))*2048 + s0 + sl] = tile[d][sl];
  }
}

// ---------------- NT GEMM: C[M][N] f32 = A[M][K]bf16 @ B[N][K]^T bf16 ----------------
// block 256 = 4 waves (2x2), 64x64 per wave, 128x128 per block. direct-global loads.
__global__ __launch_bounds__(256) void gemm_nt(const ushort_t* __restrict__ A,
                                               const ushort_t* __restrict__ B,
                                               float* __restrict__ C,
                                               int M, int N, int K){
  const int l = threadIdx.x & 63, w = threadIdx.x >> 6;
  const int g = l >> 4, c = l & 15;
  const int wr = w >> 1, wc = w & 1;
  const long m0 = (long)blockIdx.x*128 + wr*64;
  const long n0 = (long)blockIdx.y*128 + wc*64;
  f32x4 acc[4][4] = {};
  const ushort_t* ap = A + (m0 + c)*K + g*8;
  const ushort_t* bp = B + (n0 + c)*K + g*8;
  for (int k0 = 0; k0 < K; k0 += 32){
    short8 af[4], bf[4];
#pragma unroll
    for (int i = 0; i < 4; ++i) af[i] = *reinterpret_cast<const short8*>(ap + (long)i*16*K + k0);
#pragma unroll
    for (int j = 0; j < 4; ++j) bf[j] = *reinterpret_cast<const short8*>(bp + (long)j*16*K + k0);
#pragma unroll
    for (int i = 0; i < 4; ++i)
#pragma unroll
      for (int j = 0; j < 4; ++j)
        acc[i][j] = __builtin_amdgcn_mfma_f32_16x16x32_bf16(af[i], bf[j], acc[i][j], 0, 0, 0);
  }
#pragma unroll
  for (int i = 0; i < 4; ++i)
#pragma unroll
    for (int j = 0; j < 4; ++j)
#pragma unroll
      for (int r = 0; r < 4; ++r)
        C[(m0 + i*16 + g*4 + r)*(long)N + n0 + j*16 + c] = acc[i][j][r];
}

// ---------------- flash attention ----------------
// 1 wave per block. 16 q-rows per block, KV tiles of 32. causal.
// Q,K: (B,S,DIM) bf16 (Q pre-scaled by 1/sqrt(Dh)); Vt: (B*H, Dh, S) bf16; O: (B,S,DIM) bf16
__global__ __launch_bounds__(64) void attn_kernel(const ushort_t* __restrict__ Q,
                                                  const ushort_t* __restrict__ Kr,
                                                  const ushort_t* __restrict__ Vt,
                                                  ushort_t* __restrict__ O){
  const int l = threadIdx.x;
  const int g = l >> 4, c = l & 15;
  const int qt = blockIdx.x, bh = blockIdx.y;
  const int b = bh >> 4, h = bh & 15;
  const int q0 = qt * 16;

  short8 qf[4];
  const long qbase = ((long)(b*2048 + q0 + c))*2048 + h*128 + g*8;
#pragma unroll
  for (int ds = 0; ds < 4; ++ds) qf[ds] = *reinterpret_cast<const short8*>(Q + qbase + ds*32);

  f32x4 o[8] = {};
  float m[4], lsum[4];
#pragma unroll
  for (int r = 0; r < 4; ++r){ m[r] = -1e30f; lsum[r] = 0.f; }

  __shared__ ushort_t p_lds[16][40];   // stride 40*2=80B (16B multiple)
  const ushort_t* kbase = Kr + ((long)(b*2048))*2048 + h*128 + g*8;
  const ushort_t* vbase = Vt + ((long)bh*128)*2048 + g*8;

  for (int kv0 = 0; kv0 <= q0 + 15; kv0 += 32){
    f32x4 s[2] = {};
#pragma unroll
    for (int t = 0; t < 2; ++t)
#pragma unroll
      for (int ds = 0; ds < 4; ++ds){
        short8 kf = *reinterpret_cast<const short8*>(kbase + (long)(kv0 + 16*t + c)*2048 + ds*32);
        s[t] = __builtin_amdgcn_mfma_f32_16x16x32_bf16(qf[ds], kf, s[t], 0, 0, 0);
      }
    if (kv0 + 31 > q0){   // tile touches the diagonal: mask kv > q
#pragma unroll
      for (int t = 0; t < 2; ++t)
#pragma unroll
        for (int r = 0; r < 4; ++r)
          if (kv0 + 16*t + c > q0 + g*4 + r) s[t][r] = -1e30f;
    }
    float alpha[4];
#pragma unroll
    for (int r = 0; r < 4; ++r){
      float tm = fmaxf(s[0][r], s[1][r]);
#pragma unroll
      for (int off = 1; off < 16; off <<= 1) tm = fmaxf(tm, __shfl_xor(tm, off, 64));
      float mn = fmaxf(m[r], tm);
      alpha[r] = __expf(m[r] - mn);
      float ps = 0.f;
#pragma unroll
      for (int t = 0; t < 2; ++t){ float p = __expf(s[t][r] - mn); s[t][r] = p; ps += p; }
#pragma unroll
      for (int off = 1; off < 16; off <<= 1) ps += __shfl_xor(ps, off, 64);
      lsum[r] = lsum[r]*alpha[r] + ps;
      m[r] = mn;
    }
#pragma unroll
    for (int dt = 0; dt < 8; ++dt)
#pragma unroll
      for (int r = 0; r < 4; ++r) o[dt][r] *= alpha[r];

    __syncthreads();   // previous p_frag read done before overwrite
#pragma unroll
    for (int t = 0; t < 2; ++t)
#pragma unroll
      for (int r = 0; r < 4; ++r)
        p_lds[g*4 + r][c + 16*t] = f2bf(s[t][r]);
    __syncthreads();
    short8 pf = *reinterpret_cast<const short8*>(&p_lds[c][g*8]);
#pragma unroll
    for (int dt = 0; dt < 8; ++dt){
      short8 vf = *reinterpret_cast<const short8*>(vbase + (long)(16*dt + c)*2048 + kv0);
      o[dt] = __builtin_amdgcn_mfma_f32_16x16x32_bf16(pf, vf, o[dt], 0, 0, 0);
    }
  }
#pragma unroll
  for (int r = 0; r < 4; ++r){
    float inv = 1.f / lsum[r];
#pragma unroll
    for (int dt = 0; dt < 8; ++dt) o[dt][r] *= inv;
  }
  const long obase = ((long)(b*2048 + q0 + g*4))*2048 + h*128 + c;
#pragma unroll
  for (int dt = 0; dt < 8; ++dt)
#pragma unroll
    for (int r = 0; r < 4; ++r)
      O[obase + (long)r*2048 + dt*16] = f2bf(o[dt][r]);
}

// ---------------- launcher ----------------
extern "C" void kernel_launch(void* const* d_in, const int* in_sizes, int n_in,
                              void* d_out, int out_size, void* d_ws, size_t ws_size,
                              hipStream_t stream){
  const float* x    = (const float*)d_in[0];
  const float* cosb = (const float*)d_in[1];
  const float* sinb = (const float*)d_in[2];
  const float* wq   = (const float*)d_in[3];
  const float* wk   = (const float*)d_in[4];
  const float* wv   = (const float*)d_in[5];
  const float* wo   = (const float*)d_in[6];
  float* out = (float*)d_out;

  const int S = 2048, DIM = 2048;
  const long MN = 4096;               // B*S

  char* ws = (char*)d_ws;
  ushort_t* xb    = (ushort_t*)(ws);                 // 16MB
  ushort_t* wqb   = (ushort_t*)(ws + (16l<<20));     // 8MB each
  ushort_t* wkb   = (ushort_t*)(ws + (24l<<20));
  ushort_t* wvb   = (ushort_t*)(ws + (32l<<20));
  ushort_t* wob   = (ushort_t*)(ws + (40l<<20));
  float*    stage = (float*)(ws + (48l<<20));        // 32MB
  ushort_t* qr    = (ushort_t*)(ws + (80l<<20));     // 16MB
  ushort_t* kr    = (ushort_t*)(ws + (96l<<20));     // 16MB
  ushort_t* vt    = (ushort_t*)(ws + (112l<<20));    // 16MB -> total 128MB
  ushort_t* attnb = (ushort_t*)(ws + (48l<<20));     // alias stage (free by then)

  const long xn4 = MN*DIM/4, wn4 = (long)DIM*DIM/4;
  cast_bf16_kernel<<<(int)((xn4+255)/256), 256, 0, stream>>>(x,  xb,  xn4);
  cast_bf16_kernel<<<(int)((wn4+255)/256), 256, 0, stream>>>(wq, wqb, wn4);
  cast_bf16_kernel<<<(int)((wn4+255)/256), 256, 0, stream>>>(wk, wkb, wn4);
  cast_bf16_kernel<<<(int)((wn4+255)/256), 256, 0, stream>>>(wv, wvb, wn4);
  cast_bf16_kernel<<<(int)((wn4+255)/256), 256, 0, stream>>>(wo, wob, wn4);

  dim3 ggrid(MN/128, DIM/128);
  const int ropeBlocks = (2*2048*16*64)/256;

  // Q = x @ wq^T ; rope+scale -> qr
  gemm_nt<<<ggrid, 256, 0, stream>>>(xb, wqb, stage, (int)MN, DIM, DIM);
  rope_kernel<<<ropeBlocks, 256, 0, stream>>>(stage, cosb, sinb, qr, 0.08838834764831845f);
  // K
  gemm_nt<<<ggrid, 256, 0, stream>>>(xb, wkb, stage, (int)MN, DIM, DIM);
  rope_kernel<<<ropeBlocks, 256, 0, stream>>>(stage, cosb, sinb, kr, 1.0f);
  // V -> transposed bf16
  gemm_nt<<<ggrid, 256, 0, stream>>>(xb, wvb, stage, (int)MN, DIM, DIM);
  vt_kernel<<<dim3(S/64, 32), 256, 0, stream>>>(stage, vt);
  // attention
  attn_kernel<<<dim3(S/16, 32), 64, 0, stream>>>(qr, kr, vt, attnb);
  // output projection
  gemm_nt<<<ggrid, 256, 0, stream>>>(attnb, wob, out, (int)MN, DIM, DIM);
}

// Round 3
// 448.918 us; speedup vs baseline: 1.9677x; 1.9677x over previous
//
#include <hip/hip_runtime.h>

typedef short short8 __attribute__((ext_vector_type(8)));
typedef float f32x4 __attribute__((ext_vector_type(4)));
typedef unsigned short ushort_t;

__device__ __forceinline__ unsigned short f2bf(float f){
  unsigned int u = __builtin_bit_cast(unsigned int, f);
  u += 0x7FFFu + ((u >> 16) & 1u);
  return (unsigned short)(u >> 16);
}

__device__ __forceinline__ void gload_lds16(const void* g, void* l){
  __builtin_amdgcn_global_load_lds((const __attribute__((address_space(1))) unsigned int*)g,
                                   (__attribute__((address_space(3))) unsigned int*)l, 16, 0, 0);
}

// ---------------- elementwise casts ----------------
__global__ __launch_bounds__(256) void cast_bf16_kernel(const float* __restrict__ in,
                                                        ushort_t* __restrict__ out, long n4){
  long i = (long)blockIdx.x*256 + threadIdx.x;
  if (i >= n4) return;
  const float4 v = reinterpret_cast<const float4*>(in)[i];
  ushort4 o; o.x=f2bf(v.x); o.y=f2bf(v.y); o.z=f2bf(v.z); o.w=f2bf(v.w);
  reinterpret_cast<ushort4*>(out)[i] = o;
}

// ---------------- RoPE (+ optional 1/sqrt(Dh) fold) ----------------
__global__ __launch_bounds__(256) void rope_kernel(const float* __restrict__ X,
                                                   const float* __restrict__ cosb,
                                                   const float* __restrict__ sinb,
                                                   ushort_t* __restrict__ Out, float scale){
  long idx = (long)blockIdx.x*256 + threadIdx.x;
  int d = idx & 63;
  long rest = idx >> 6;
  int h = rest & 15; rest >>= 4;
  int s = rest & 2047;
  int b = (int)(rest >> 11);
  long base = ((long)(b*2048 + s))*2048 + h*128;
  float x1 = X[base + d], x2 = X[base + 64 + d];
  float cc = cosb[s*64 + d], ss = sinb[s*64 + d];
  Out[base + d]      = f2bf((x1*cc - x2*ss)*scale);
  Out[base + 64 + d] = f2bf((x1*ss + x2*cc)*scale);
}

// ---------------- V cast + transpose to (B*H, Dh, S) ----------------
__global__ __launch_bounds__(256) void vt_kernel(const float* __restrict__ vf,
                                                 ushort_t* __restrict__ vt){
  const int s0 = blockIdx.x*64;
  const int bh = blockIdx.y;
  const int b = bh >> 4, h = bh & 15;
  __shared__ ushort_t tile[128][66];
  for (int it = 0; it < 32; ++it){
    int idx = it*256 + threadIdx.x;
    int sl = idx >> 7, d = idx & 127;
    float v = vf[((long)(b*2048 + s0 + sl))*2048 + h*128 + d];
    tile[d][sl] = f2bf(v);
  }
  __syncthreads();
  for (int it = 0; it < 32; ++it){
    int idx = it*256 + threadIdx.x;
    int d = idx >> 6, sl = idx & 63;
    vt[((long)(bh*128 + d))*2048 + s0 + sl] = tile[d][sl];
  }
}

// ---------------- m97-style NT GEMM: C[M][N] f32 = A[M][K]bf16 @ B[N][K]^T ----------------
// 128x128 tile, BK=32, 4 waves (2x2), global_load_lds width 16, 2 barriers/K-step.
__global__ __launch_bounds__(256) void gemm_nt_lds(const ushort_t* __restrict__ A,
                                                   const ushort_t* __restrict__ B,
                                                   float* __restrict__ C,
                                                   int M, int N, int K){
  const int tid = threadIdx.x;
  const int l = tid & 63;
  const int g = l >> 4, c = l & 15;
  const int w = tid >> 6, wr = w >> 1, wc = w & 1;
  const long m0 = (long)blockIdx.x*128, n0 = (long)blockIdx.y*128;
  __shared__ ushort_t lds_a[128*32];
  __shared__ ushort_t lds_b[128*32];
  f32x4 acc[4][4] = {};
  const int q1 = tid, q2 = 256 + tid;   // 16B-chunk indices (512 chunks per 8KB tile)
  const ushort_t* a1 = A + (m0 + (q1>>2))*(long)K + (q1&3)*8;
  const ushort_t* a2 = A + (m0 + (q2>>2))*(long)K + (q2&3)*8;
  const ushort_t* b1 = B + (n0 + (q1>>2))*(long)K + (q1&3)*8;
  const ushort_t* b2 = B + (n0 + (q2>>2))*(long)K + (q2&3)*8;
  for (int k0 = 0; k0 < K; k0 += 32){
    __syncthreads();
    gload_lds16(a1 + k0, &lds_a[q1*8]);
    gload_lds16(a2 + k0, &lds_a[q2*8]);
    gload_lds16(b1 + k0, &lds_b[q1*8]);
    gload_lds16(b2 + k0, &lds_b[q2*8]);
    __syncthreads();
    short8 af[4], bf[4];
#pragma unroll
    for (int i = 0; i < 4; ++i) af[i] = *(const short8*)&lds_a[(wr*64 + i*16 + c)*32 + g*8];
#pragma unroll
    for (int j = 0; j < 4; ++j) bf[j] = *(const short8*)&lds_b[(wc*64 + j*16 + c)*32 + g*8];
#pragma unroll
    for (int i = 0; i < 4; ++i)
#pragma unroll
      for (int j = 0; j < 4; ++j)
        acc[i][j] = __builtin_amdgcn_mfma_f32_16x16x32_bf16(af[i], bf[j], acc[i][j], 0, 0, 0);
  }
#pragma unroll
  for (int i = 0; i < 4; ++i)
#pragma unroll
    for (int j = 0; j < 4; ++j)
#pragma unroll
      for (int r = 0; r < 4; ++r)
        C[(m0 + wr*64 + i*16 + g*4 + r)*(long)N + n0 + wc*64 + j*16 + c] = acc[i][j][r];
}

// ---------------- flash attention: 4 waves, QBLK=64, KVBLK=64 LDS-staged ----------------
// Q,K: (B,S,DIM) bf16 (Q pre-scaled); Vt: (B*H, Dh, S) bf16; O: (B,S,DIM) bf16
__global__ __launch_bounds__(256) void attn_kernel(const ushort_t* __restrict__ Q,
                                                   const ushort_t* __restrict__ Kr,
                                                   const ushort_t* __restrict__ Vt,
                                                   ushort_t* __restrict__ O){
  const int tid = threadIdx.x;
  const int l = tid & 63, w = tid >> 6;
  const int g = l >> 4, c = l & 15;
  const int qt = (int)gridDim.x - 1 - (int)blockIdx.x;   // heavy tiles dispatched first
  const int bh = blockIdx.y;
  const int b = bh >> 4, h = bh & 15;
  const int q0 = qt * 64;
  const int qw0 = q0 + w * 16;

  __shared__ ushort_t k_lds[64*128];    // swizzled: phys = logical ^ ((row&7)<<3) elems
  __shared__ ushort_t vt_lds[128*64];   // swizzled: phys = logical ^ ((d&7)<<3) elems
  __shared__ ushort_t p_lds[4*16*72];   // per-wave P tile, padded stride 72

  // Q fragments (held in registers)
  short8 qf[4];
  const long qbase = ((long)(b*2048 + qw0 + c))*2048 + h*128 + g*8;
#pragma unroll
  for (int ds = 0; ds < 4; ++ds) qf[ds] = *(const short8*)(Q + qbase + ds*32);

  // staging pointers (chunk q = i*256 + tid; K: r=q>>4,j=q&15; V: d=q>>3,jj=q&7)
  const ushort_t* ksrc[4]; const ushort_t* vsrc[4];
  ushort_t* kdst[4]; ushort_t* vdst[4];
#pragma unroll
  for (int i = 0; i < 4; ++i){
    int q = i*256 + tid;
    int r = q >> 4, j = q & 15;
    int jp = j ^ (r & 7);
    ksrc[i] = Kr + ((long)(b*2048 + r))*2048 + h*128 + jp*8;
    kdst[i] = &k_lds[q*8];
    int d = q >> 3, jj = q & 7;
    int jjp = jj ^ (d & 7);
    vsrc[i] = Vt + ((long)(bh*128 + d))*2048 + jjp*8;
    vdst[i] = &vt_lds[q*8];
  }

  f32x4 o[8] = {};
  float m[4], lsum[4];
#pragma unroll
  for (int r = 0; r < 4; ++r){ m[r] = -1e30f; lsum[r] = 0.f; }
  const int sw = (c & 7) << 3;

  for (int kv0 = 0; kv0 < q0 + 64; kv0 += 64){
    __syncthreads();     // previous tile's LDS reads complete
#pragma unroll
    for (int i = 0; i < 4; ++i){
      gload_lds16(ksrc[i] + (long)kv0*2048, kdst[i]);
      gload_lds16(vsrc[i] + kv0, vdst[i]);
    }
    __syncthreads();     // staging complete (vmcnt(0) before barrier)

    if (kv0 <= qw0 + 15){
      // ---- QK^T: 16 q-rows x 64 kv ----
      f32x4 s[4] = {};
#pragma unroll
      for (int t = 0; t < 4; ++t){
        const int row = 16*t + c;
#pragma unroll
        for (int ds = 0; ds < 4; ++ds){
          short8 kf = *(const short8*)&k_lds[(row*128 + ds*32 + g*8) ^ sw];
          s[t] = __builtin_amdgcn_mfma_f32_16x16x32_bf16(qf[ds], kf, s[t], 0, 0, 0);
        }
      }
      // ---- causal mask ----
      if (kv0 + 63 > qw0){
#pragma unroll
        for (int t = 0; t < 4; ++t)
#pragma unroll
          for (int r = 0; r < 4; ++r)
            if (kv0 + 16*t + c > qw0 + g*4 + r) s[t][r] = -1e30f;
      }
      // ---- online softmax (16-lane groups share a q-row) ----
      float alpha[4];
#pragma unroll
      for (int r = 0; r < 4; ++r){
        float tm = fmaxf(fmaxf(s[0][r], s[1][r]), fmaxf(s[2][r], s[3][r]));
#pragma unroll
        for (int off = 1; off < 16; off <<= 1) tm = fmaxf(tm, __shfl_xor(tm, off, 64));
        float mn = fmaxf(m[r], tm);
        alpha[r] = __expf(m[r] - mn);
        float ps = 0.f;
#pragma unroll
        for (int t = 0; t < 4; ++t){ float p = __expf(s[t][r] - mn); s[t][r] = p; ps += p; }
#pragma unroll
        for (int off = 1; off < 16; off <<= 1) ps += __shfl_xor(ps, off, 64);
        lsum[r] = lsum[r]*alpha[r] + ps;
        m[r] = mn;
      }
#pragma unroll
      for (int dt = 0; dt < 8; ++dt)
#pragma unroll
        for (int r = 0; r < 4; ++r) o[dt][r] *= alpha[r];
      // ---- P -> LDS (per-wave region, no cross-wave sync needed) ----
#pragma unroll
      for (int t = 0; t < 4; ++t)
#pragma unroll
        for (int r = 0; r < 4; ++r)
          p_lds[(w*16 + g*4 + r)*72 + 16*t + c] = f2bf(s[t][r]);
      // ---- PV ----
#pragma unroll
      for (int kc = 0; kc < 2; ++kc){
        short8 pf = *(const short8*)&p_lds[(w*16 + c)*72 + kc*32 + g*8];
#pragma unroll
        for (int dt = 0; dt < 8; ++dt){
          short8 vf = *(const short8*)&vt_lds[(((16*dt + c)*64) + kc*32 + g*8) ^ sw];
          o[dt] = __builtin_amdgcn_mfma_f32_16x16x32_bf16(pf, vf, o[dt], 0, 0, 0);
        }
      }
    }
  }
#pragma unroll
  for (int r = 0; r < 4; ++r){
    float inv = 1.f / lsum[r];
#pragma unroll
    for (int dt = 0; dt < 8; ++dt) o[dt][r] *= inv;
  }
  const long obase = ((long)(b*2048 + qw0 + g*4))*2048 + h*128 + c;
#pragma unroll
  for (int dt = 0; dt < 8; ++dt)
#pragma unroll
    for (int r = 0; r < 4; ++r)
      O[obase + (long)r*2048 + dt*16] = f2bf(o[dt][r]);
}

// ---------------- launcher ----------------
extern "C" void kernel_launch(void* const* d_in, const int* in_sizes, int n_in,
                              void* d_out, int out_size, void* d_ws, size_t ws_size,
                              hipStream_t stream){
  const float* x    = (const float*)d_in[0];
  const float* cosb = (const float*)d_in[1];
  const float* sinb = (const float*)d_in[2];
  const float* wq   = (const float*)d_in[3];
  const float* wk   = (const float*)d_in[4];
  const float* wv   = (const float*)d_in[5];
  const float* wo   = (const float*)d_in[6];
  float* out = (float*)d_out;

  const int S = 2048, DIM = 2048;
  const long MN = 4096;

  char* ws = (char*)d_ws;
  ushort_t* xb    = (ushort_t*)(ws);
  ushort_t* wqb   = (ushort_t*)(ws + (16l<<20));
  ushort_t* wkb   = (ushort_t*)(ws + (24l<<20));
  ushort_t* wvb   = (ushort_t*)(ws + (32l<<20));
  ushort_t* wob   = (ushort_t*)(ws + (40l<<20));
  float*    stage = (float*)(ws + (48l<<20));
  ushort_t* qr    = (ushort_t*)(ws + (80l<<20));
  ushort_t* kr    = (ushort_t*)(ws + (96l<<20));
  ushort_t* vt    = (ushort_t*)(ws + (112l<<20));
  ushort_t* attnb = (ushort_t*)(ws + (48l<<20));

  const long xn4 = MN*DIM/4, wn4 = (long)DIM*DIM/4;
  cast_bf16_kernel<<<(int)((xn4+255)/256), 256, 0, stream>>>(x,  xb,  xn4);
  cast_bf16_kernel<<<(int)((wn4+255)/256), 256, 0, stream>>>(wq, wqb, wn4);
  cast_bf16_kernel<<<(int)((wn4+255)/256), 256, 0, stream>>>(wk, wkb, wn4);
  cast_bf16_kernel<<<(int)((wn4+255)/256), 256, 0, stream>>>(wv, wvb, wn4);
  cast_bf16_kernel<<<(int)((wn4+255)/256), 256, 0, stream>>>(wo, wob, wn4);

  dim3 ggrid(MN/128, DIM/128);
  const int ropeBlocks = (2*2048*16*64)/256;

  gemm_nt_lds<<<ggrid, 256, 0, stream>>>(xb, wqb, stage, (int)MN, DIM, DIM);
  rope_kernel<<<ropeBlocks, 256, 0, stream>>>(stage, cosb, sinb, qr, 0.08838834764831845f);
  gemm_nt_lds<<<ggrid, 256, 0, stream>>>(xb, wkb, stage, (int)MN, DIM, DIM);
  rope_kernel<<<ropeBlocks, 256, 0, stream>>>(stage, cosb, sinb, kr, 1.0f);
  gemm_nt_lds<<<ggrid, 256, 0, stream>>>(xb, wvb, stage, (int)MN, DIM, DIM);
  vt_kernel<<<dim3(S/64, 32), 256, 0, stream>>>(stage, vt);
  attn_kernel<<<dim3(S/64, 32), 256, 0, stream>>>(qr, kr, vt, attnb);
  gemm_nt_lds<<<ggrid, 256, 0, stream>>>(attnb, wob, out, (int)MN, DIM, DIM);
}

// Round 4
// 398.414 us; speedup vs baseline: 2.2172x; 1.1268x over previous
//
#include <hip/hip_runtime.h>

typedef short short8 __attribute__((ext_vector_type(8)));
typedef float f32x4 __attribute__((ext_vector_type(4)));
typedef unsigned short ushort_t;

__device__ __forceinline__ unsigned short f2bf(float f){
  unsigned int u = __builtin_bit_cast(unsigned int, f);
  u += 0x7FFFu + ((u >> 16) & 1u);
  return (unsigned short)(u >> 16);
}
__device__ __forceinline__ float bf2f(unsigned short u){
  return __builtin_bit_cast(float, ((unsigned int)u) << 16);
}
__device__ __forceinline__ void gload_lds16(const void* g, void* l){
  __builtin_amdgcn_global_load_lds((const __attribute__((address_space(1))) unsigned int*)g,
                                   (__attribute__((address_space(3))) unsigned int*)l, 16, 0, 0);
}

// ---------------- elementwise casts ----------------
__global__ __launch_bounds__(256) void cast_bf16_kernel(const float* __restrict__ in,
                                                        ushort_t* __restrict__ out, long n4){
  long i = (long)blockIdx.x*256 + threadIdx.x;
  if (i >= n4) return;
  const float4 v = reinterpret_cast<const float4*>(in)[i];
  ushort4 o; o.x=f2bf(v.x); o.y=f2bf(v.y); o.z=f2bf(v.z); o.w=f2bf(v.w);
  reinterpret_cast<ushort4*>(out)[i] = o;
}

// ---------------- RoPE on bf16 stage (+ optional scale fold) ----------------
__global__ __launch_bounds__(256) void rope_kernel(const ushort_t* __restrict__ X,
                                                   const float* __restrict__ cosb,
                                                   const float* __restrict__ sinb,
                                                   ushort_t* __restrict__ Out, float scale){
  long idx = (long)blockIdx.x*256 + threadIdx.x;    // B*S*H*16 threads
  int dq = (int)(idx & 15);
  long rest = idx >> 4;
  int h = (int)(rest & 15); rest >>= 4;
  int s = (int)(rest & 2047);
  int b = (int)(rest >> 11);
  long base = ((long)(b*2048 + s))*2048 + h*128;
  int d0 = dq*4;
  ushort4 x1 = *(const ushort4*)&X[base + d0];
  ushort4 x2 = *(const ushort4*)&X[base + 64 + d0];
  float4 cc = *(const float4*)&cosb[s*64 + d0];
  float4 ss = *(const float4*)&sinb[s*64 + d0];
  ushort4 o1, o2;
  { float a=bf2f(x1.x), bb=bf2f(x2.x); o1.x=f2bf((a*cc.x-bb*ss.x)*scale); o2.x=f2bf((a*ss.x+bb*cc.x)*scale); }
  { float a=bf2f(x1.y), bb=bf2f(x2.y); o1.y=f2bf((a*cc.y-bb*ss.y)*scale); o2.y=f2bf((a*ss.y+bb*cc.y)*scale); }
  { float a=bf2f(x1.z), bb=bf2f(x2.z); o1.z=f2bf((a*cc.z-bb*ss.z)*scale); o2.z=f2bf((a*ss.z+bb*cc.z)*scale); }
  { float a=bf2f(x1.w), bb=bf2f(x2.w); o1.w=f2bf((a*cc.w-bb*ss.w)*scale); o2.w=f2bf((a*ss.w+bb*cc.w)*scale); }
  *(ushort4*)&Out[base + d0] = o1;
  *(ushort4*)&Out[base + 64 + d0] = o2;
}

// ---------------- V transpose (bf16 in) to (B*H, Dh, S) ----------------
__global__ __launch_bounds__(256) void vt_kernel(const ushort_t* __restrict__ vf,
                                                 ushort_t* __restrict__ vt){
  const int s0 = blockIdx.x*64;
  const int bh = blockIdx.y;
  const int b = bh >> 4, h = bh & 15;
  const int tid = threadIdx.x;
  __shared__ ushort_t tile[128][72];
#pragma unroll
  for (int i = 0; i < 4; ++i){
    int q = i*256 + tid;                 // 1024 chunks of 8
    int sl = q >> 4, dc = (q & 15)*8;
    short8 v = *(const short8*)&vf[((long)(b*2048 + s0 + sl))*2048 + h*128 + dc];
#pragma unroll
    for (int k = 0; k < 8; ++k) tile[dc + k][sl] = (ushort_t)v[k];
  }
  __syncthreads();
#pragma unroll
  for (int i = 0; i < 4; ++i){
    int q = i*256 + tid;
    int d = q >> 3, sc = (q & 7)*8;
    *(short8*)&vt[((long)(bh*128 + d))*2048 + s0 + sc] = *(const short8*)&tile[d][sc];
  }
}

// ---------------- m97-style NT GEMM: C = A[M][K]bf16 @ B[N][K]^T, CT out ----------------
template<typename CT>
__global__ __launch_bounds__(256) void gemm_nt_lds(const ushort_t* __restrict__ A,
                                                   const ushort_t* __restrict__ B,
                                                   CT* __restrict__ C,
                                                   int M, int N, int K){
  const int tid = threadIdx.x;
  const int l = tid & 63;
  const int g = l >> 4, c = l & 15;
  const int w = tid >> 6, wr = w >> 1, wc = w & 1;
  const long m0 = (long)blockIdx.x*128, n0 = (long)blockIdx.y*128;
  __shared__ ushort_t lds_a[128*32];
  __shared__ ushort_t lds_b[128*32];
  f32x4 acc[4][4] = {};
  const int q1 = tid, q2 = 256 + tid;
  const ushort_t* a1 = A + (m0 + (q1>>2))*(long)K + (q1&3)*8;
  const ushort_t* a2 = A + (m0 + (q2>>2))*(long)K + (q2&3)*8;
  const ushort_t* b1 = B + (n0 + (q1>>2))*(long)K + (q1&3)*8;
  const ushort_t* b2 = B + (n0 + (q2>>2))*(long)K + (q2&3)*8;
  for (int k0 = 0; k0 < K; k0 += 32){
    __syncthreads();
    gload_lds16(a1 + k0, &lds_a[q1*8]);
    gload_lds16(a2 + k0, &lds_a[q2*8]);
    gload_lds16(b1 + k0, &lds_b[q1*8]);
    gload_lds16(b2 + k0, &lds_b[q2*8]);
    __syncthreads();
    short8 af[4], bf[4];
#pragma unroll
    for (int i = 0; i < 4; ++i) af[i] = *(const short8*)&lds_a[(wr*64 + i*16 + c)*32 + g*8];
#pragma unroll
    for (int j = 0; j < 4; ++j) bf[j] = *(const short8*)&lds_b[(wc*64 + j*16 + c)*32 + g*8];
#pragma unroll
    for (int i = 0; i < 4; ++i)
#pragma unroll
      for (int j = 0; j < 4; ++j)
        acc[i][j] = __builtin_amdgcn_mfma_f32_16x16x32_bf16(af[i], bf[j], acc[i][j], 0, 0, 0);
  }
#pragma unroll
  for (int i = 0; i < 4; ++i)
#pragma unroll
    for (int j = 0; j < 4; ++j)
#pragma unroll
      for (int r = 0; r < 4; ++r){
        long off = (m0 + wr*64 + i*16 + g*4 + r)*(long)N + n0 + wc*64 + j*16 + c;
        if constexpr (sizeof(CT) == 2) C[off] = (CT)f2bf(acc[i][j][r]);
        else                           C[off] = acc[i][j][r];
      }
}

// ---------------- flash attention: 4 waves, QBLK=64, KVBLK=64, K-dbuf 2-phase ----------------
// Swapped QK^T: s = mfma(K,Q) -> lane holds q-row = c, kv = 16t+4g+r (lane-local softmax).
__global__ __launch_bounds__(256) void attn_kernel(const ushort_t* __restrict__ Q,
                                                   const ushort_t* __restrict__ Kr,
                                                   const ushort_t* __restrict__ Vt,
                                                   ushort_t* __restrict__ O){
  const int tid = threadIdx.x;
  const int l = tid & 63, w = tid >> 6;
  const int g = l >> 4, c = l & 15;
  const int qt = (int)gridDim.x - 1 - (int)blockIdx.x;   // heavy tiles first
  const int bh = blockIdx.y;
  const int b = bh >> 4, h = bh & 15;
  const int q0 = qt * 64;
  const int qw0 = q0 + w * 16;
  const int nt = qt + 1;

  __shared__ ushort_t k_lds[2][64*128];   // K double buffer (read early in tile)
  __shared__ ushort_t v_lds[128*64];      // V single buffer (staged at tile start, read late)
  __shared__ ushort_t p_lds[4][16*72];    // per-wave P

  short8 qf[4];
  const long qbase = ((long)(b*2048 + qw0 + c))*2048 + h*128 + g*8;
#pragma unroll
  for (int ds = 0; ds < 4; ++ds) qf[ds] = *(const short8*)(Q + qbase + ds*32);

  const ushort_t* ksrc[4]; const ushort_t* vsrc[4];
  ushort_t* kdst[4]; ushort_t* vdst[4];
#pragma unroll
  for (int i = 0; i < 4; ++i){
    int q = i*256 + tid;                 // 1024 chunks of 16B
    int r = q >> 4, j = q & 15;
    ksrc[i] = Kr + ((long)(b*2048 + r))*2048 + h*128 + (j ^ (r & 7))*8;
    kdst[i] = &k_lds[0][q*8];
    int d = q >> 3, jj = q & 7;
    vsrc[i] = Vt + ((long)(bh*128 + d))*2048 + (jj ^ (d & 7))*8;
    vdst[i] = &v_lds[q*8];
  }

  f32x4 o[8] = {};
  float m = -1e30f, lsum = 0.f;
  const int sw = (c & 7) << 3;

  // prologue: stage K tile 0 into buf 0
#pragma unroll
  for (int i = 0; i < 4; ++i) gload_lds16(ksrc[i], kdst[i]);
  __syncthreads();
  int kb = 0;

  for (int t = 0; t < nt; ++t){
    const int kv0 = t*64;
    if (t + 1 < nt){                      // prefetch K[t+1] into kb^1
#pragma unroll
      for (int i = 0; i < 4; ++i)
        gload_lds16(ksrc[i] + (long)(kv0 + 64)*2048, kdst[i] + (kb^1)*8192);
    }
#pragma unroll
    for (int i = 0; i < 4; ++i)           // stage V[t]
      gload_lds16(vsrc[i] + kv0, vdst[i]);

    // ---- QK^T (swapped) from k_lds[kb] ----
    f32x4 s[4] = {};
#pragma unroll
    for (int t4 = 0; t4 < 4; ++t4){
      const int row = 16*t4 + c;
#pragma unroll
      for (int ds = 0; ds < 4; ++ds){
        short8 kf = *(const short8*)&k_lds[kb][(row*128 + ds*32 + g*8) ^ sw];
        s[t4] = __builtin_amdgcn_mfma_f32_16x16x32_bf16(kf, qf[ds], s[t4], 0, 0, 0);
      }
    }
    // ---- causal mask: q = qw0+c, kv = kv0+16t4+4g+r ----
    if (kv0 + 63 > qw0){
      const int qg = qw0 + c;
#pragma unroll
      for (int t4 = 0; t4 < 4; ++t4)
#pragma unroll
        for (int r = 0; r < 4; ++r)
          if (kv0 + 16*t4 + 4*g + r > qg) s[t4][r] = -1e30f;
    }
    // ---- per-lane online softmax (row = c) ----
    float tm = -1e30f;
#pragma unroll
    for (int t4 = 0; t4 < 4; ++t4)
      tm = fmaxf(tm, fmaxf(fmaxf(s[t4][0], s[t4][1]), fmaxf(s[t4][2], s[t4][3])));
    tm = fmaxf(tm, __shfl_xor(tm, 16, 64));
    tm = fmaxf(tm, __shfl_xor(tm, 32, 64));
    float mn = fmaxf(m, tm);
    float al = __expf(m - mn);
    float ps = 0.f;
#pragma unroll
    for (int t4 = 0; t4 < 4; ++t4)
#pragma unroll
      for (int r = 0; r < 4; ++r){ float p = __expf(s[t4][r] - mn); s[t4][r] = p; ps += p; }
    ps += __shfl_xor(ps, 16, 64);
    ps += __shfl_xor(ps, 32, 64);
    lsum = lsum*al + ps;
    m = mn;
    float alr[4];
#pragma unroll
    for (int r = 0; r < 4; ++r) alr[r] = __shfl(al, 4*g + r, 64);
#pragma unroll
    for (int dt = 0; dt < 8; ++dt)
#pragma unroll
      for (int r = 0; r < 4; ++r) o[dt][r] *= alr[r];
    // ---- P write: packed b64 per t4 (kv 16t4+4g..+3 of row c) ----
#pragma unroll
    for (int t4 = 0; t4 < 4; ++t4){
      uint2 pw;
      pw.x = (unsigned)f2bf(s[t4][0]) | ((unsigned)f2bf(s[t4][1]) << 16);
      pw.y = (unsigned)f2bf(s[t4][2]) | ((unsigned)f2bf(s[t4][3]) << 16);
      *reinterpret_cast<uint2*>(&p_lds[w][c*72 + 16*t4 + 4*g]) = pw;
    }
    __syncthreads();    // V[t] staged (vmcnt drain) + all waves' QK reads of k_lds done
    // ---- PV ----
#pragma unroll
    for (int kc = 0; kc < 2; ++kc){
      short8 pf = *(const short8*)&p_lds[w][c*72 + 32*kc + 8*g];
#pragma unroll
      for (int dt = 0; dt < 8; ++dt){
        short8 vf = *(const short8*)&v_lds[(((16*dt + c)*64) + kc*32 + g*8) ^ sw];
        o[dt] = __builtin_amdgcn_mfma_f32_16x16x32_bf16(pf, vf, o[dt], 0, 0, 0);
      }
    }
    __syncthreads();    // PV reads done before next tile overwrites v_lds
    kb ^= 1;
  }

  float inv = 1.f / lsum;
  float invr[4];
#pragma unroll
  for (int r = 0; r < 4; ++r) invr[r] = __shfl(inv, 4*g + r, 64);
  const long obase = ((long)(b*2048 + qw0 + g*4))*2048 + h*128 + c;
#pragma unroll
  for (int dt = 0; dt < 8; ++dt)
#pragma unroll
    for (int r = 0; r < 4; ++r)
      O[obase + (long)r*2048 + dt*16] = f2bf(o[dt][r] * invr[r]);
}

// ---------------- launcher ----------------
extern "C" void kernel_launch(void* const* d_in, const int* in_sizes, int n_in,
                              void* d_out, int out_size, void* d_ws, size_t ws_size,
                              hipStream_t stream){
  const float* x    = (const float*)d_in[0];
  const float* cosb = (const float*)d_in[1];
  const float* sinb = (const float*)d_in[2];
  const float* wq   = (const float*)d_in[3];
  const float* wk   = (const float*)d_in[4];
  const float* wv   = (const float*)d_in[5];
  const float* wo   = (const float*)d_in[6];
  float* out = (float*)d_out;

  const int S = 2048, DIM = 2048;
  const long MN = 4096;

  char* ws = (char*)d_ws;
  ushort_t* xb    = (ushort_t*)(ws);                 // 16MB
  ushort_t* wqb   = (ushort_t*)(ws + (16l<<20));
  ushort_t* wkb   = (ushort_t*)(ws + (24l<<20));
  ushort_t* wvb   = (ushort_t*)(ws + (32l<<20));
  ushort_t* wob   = (ushort_t*)(ws + (40l<<20));
  ushort_t* stage = (ushort_t*)(ws + (48l<<20));     // 16MB bf16
  ushort_t* attnb = (ushort_t*)(ws + (64l<<20));     // 16MB
  ushort_t* qr    = (ushort_t*)(ws + (80l<<20));
  ushort_t* kr    = (ushort_t*)(ws + (96l<<20));
  ushort_t* vt    = (ushort_t*)(ws + (112l<<20));

  const long xn4 = MN*DIM/4, wn4 = (long)DIM*DIM/4;
  cast_bf16_kernel<<<(int)((xn4+255)/256), 256, 0, stream>>>(x,  xb,  xn4);
  cast_bf16_kernel<<<(int)((wn4+255)/256), 256, 0, stream>>>(wq, wqb, wn4);
  cast_bf16_kernel<<<(int)((wn4+255)/256), 256, 0, stream>>>(wk, wkb, wn4);
  cast_bf16_kernel<<<(int)((wn4+255)/256), 256, 0, stream>>>(wv, wvb, wn4);
  cast_bf16_kernel<<<(int)((wn4+255)/256), 256, 0, stream>>>(wo, wob, wn4);

  dim3 ggrid(MN/128, DIM/128);
  const int ropeBlocks = (2*2048*16*16)/256;

  gemm_nt_lds<ushort_t><<<ggrid, 256, 0, stream>>>(xb, wqb, stage, (int)MN, DIM, DIM);
  rope_kernel<<<ropeBlocks, 256, 0, stream>>>(stage, cosb, sinb, qr, 0.08838834764831845f);
  gemm_nt_lds<ushort_t><<<ggrid, 256, 0, stream>>>(xb, wkb, stage, (int)MN, DIM, DIM);
  rope_kernel<<<ropeBlocks, 256, 0, stream>>>(stage, cosb, sinb, kr, 1.0f);
  gemm_nt_lds<ushort_t><<<ggrid, 256, 0, stream>>>(xb, wvb, stage, (int)MN, DIM, DIM);
  vt_kernel<<<dim3(S/64, 32), 256, 0, stream>>>(stage, vt);
  attn_kernel<<<dim3(S/64, 32), 256, 0, stream>>>(qr, kr, vt, attnb);
  gemm_nt_lds<float><<<ggrid, 256, 0, stream>>>(attnb, wob, out, (int)MN, DIM, DIM);
}

// Round 5
// 330.828 us; speedup vs baseline: 2.6701x; 1.2043x over previous
//
#include <hip/hip_runtime.h>

typedef short short8 __attribute__((ext_vector_type(8)));
typedef float f32x4 __attribute__((ext_vector_type(4)));
typedef unsigned short ushort_t;

__device__ __forceinline__ unsigned short f2bf(float f){
  unsigned int u = __builtin_bit_cast(unsigned int, f);
  u += 0x7FFFu + ((u >> 16) & 1u);
  return (unsigned short)(u >> 16);
}
__device__ __forceinline__ float bf2f(unsigned short u){
  return __builtin_bit_cast(float, ((unsigned int)u) << 16);
}
__device__ __forceinline__ void gload_lds16(const void* g, void* l){
  __builtin_amdgcn_global_load_lds((const __attribute__((address_space(1))) unsigned int*)g,
                                   (__attribute__((address_space(3))) unsigned int*)l, 16, 0, 0);
}

// ---------------- elementwise casts ----------------
__global__ __launch_bounds__(256) void cast_bf16_kernel(const float* __restrict__ in,
                                                        ushort_t* __restrict__ out, long n4){
  long i = (long)blockIdx.x*256 + threadIdx.x;
  if (i >= n4) return;
  const float4 v = reinterpret_cast<const float4*>(in)[i];
  ushort4 o; o.x=f2bf(v.x); o.y=f2bf(v.y); o.z=f2bf(v.z); o.w=f2bf(v.w);
  reinterpret_cast<ushort4*>(out)[i] = o;
}

// 4 weight casts in one dispatch (blockIdx.y selects the weight)
__global__ __launch_bounds__(256) void cast4_bf16_kernel(const float* __restrict__ w0, const float* __restrict__ w1,
                                                         const float* __restrict__ w2, const float* __restrict__ w3,
                                                         ushort_t* __restrict__ o0, ushort_t* __restrict__ o1,
                                                         ushort_t* __restrict__ o2, ushort_t* __restrict__ o3,
                                                         long n4){
  long i = (long)blockIdx.x*256 + threadIdx.x;
  if (i >= n4) return;
  const float* in; ushort_t* out;
  switch (blockIdx.y){
    case 0: in = w0; out = o0; break;
    case 1: in = w1; out = o1; break;
    case 2: in = w2; out = o2; break;
    default: in = w3; out = o3; break;
  }
  const float4 v = reinterpret_cast<const float4*>(in)[i];
  ushort4 o; o.x=f2bf(v.x); o.y=f2bf(v.y); o.z=f2bf(v.z); o.w=f2bf(v.w);
  reinterpret_cast<ushort4*>(out)[i] = o;
}

// ---------------- RoPE on bf16 stage (+ optional scale fold) ----------------
__global__ __launch_bounds__(256) void rope_kernel(const ushort_t* __restrict__ X,
                                                   const float* __restrict__ cosb,
                                                   const float* __restrict__ sinb,
                                                   ushort_t* __restrict__ Out, float scale){
  long idx = (long)blockIdx.x*256 + threadIdx.x;    // B*S*H*16 threads
  int dq = (int)(idx & 15);
  long rest = idx >> 4;
  int h = (int)(rest & 15); rest >>= 4;
  int s = (int)(rest & 2047);
  int b = (int)(rest >> 11);
  long base = ((long)(b*2048 + s))*2048 + h*128;
  int d0 = dq*4;
  ushort4 x1 = *(const ushort4*)&X[base + d0];
  ushort4 x2 = *(const ushort4*)&X[base + 64 + d0];
  float4 cc = *(const float4*)&cosb[s*64 + d0];
  float4 ss = *(const float4*)&sinb[s*64 + d0];
  ushort4 o1, o2;
  { float a=bf2f(x1.x), bb=bf2f(x2.x); o1.x=f2bf((a*cc.x-bb*ss.x)*scale); o2.x=f2bf((a*ss.x+bb*cc.x)*scale); }
  { float a=bf2f(x1.y), bb=bf2f(x2.y); o1.y=f2bf((a*cc.y-bb*ss.y)*scale); o2.y=f2bf((a*ss.y+bb*cc.y)*scale); }
  { float a=bf2f(x1.z), bb=bf2f(x2.z); o1.z=f2bf((a*cc.z-bb*ss.z)*scale); o2.z=f2bf((a*ss.z+bb*cc.z)*scale); }
  { float a=bf2f(x1.w), bb=bf2f(x2.w); o1.w=f2bf((a*cc.w-bb*ss.w)*scale); o2.w=f2bf((a*ss.w+bb*cc.w)*scale); }
  *(ushort4*)&Out[base + d0] = o1;
  *(ushort4*)&Out[base + 64 + d0] = o2;
}

// ---------------- V transpose (bf16 in) to (B*H, Dh, S) ----------------
__global__ __launch_bounds__(256) void vt_kernel(const ushort_t* __restrict__ vf,
                                                 ushort_t* __restrict__ vt){
  const int s0 = blockIdx.x*64;
  const int bh = blockIdx.y;
  const int b = bh >> 4, h = bh & 15;
  const int tid = threadIdx.x;
  __shared__ ushort_t tile[128][72];
#pragma unroll
  for (int i = 0; i < 4; ++i){
    int q = i*256 + tid;                 // 1024 chunks of 8
    int sl = q >> 4, dc = (q & 15)*8;
    short8 v = *(const short8*)&vf[((long)(b*2048 + s0 + sl))*2048 + h*128 + dc];
#pragma unroll
    for (int k = 0; k < 8; ++k) tile[dc + k][sl] = (ushort_t)v[k];
  }
  __syncthreads();
#pragma unroll
  for (int i = 0; i < 4; ++i){
    int q = i*256 + tid;
    int d = q >> 3, sc = (q & 7)*8;
    *(short8*)&vt[((long)(bh*128 + d))*2048 + s0 + sc] = *(const short8*)&tile[d][sc];
  }
}

// ---------------- m97-style NT GEMM: C = A[M][K]bf16 @ B[N][K]^T, CT out ----------------
template<typename CT>
__global__ __launch_bounds__(256) void gemm_nt_lds(const ushort_t* __restrict__ A,
                                                   const ushort_t* __restrict__ B,
                                                   CT* __restrict__ C,
                                                   int M, int N, int K){
  const int tid = threadIdx.x;
  const int l = tid & 63;
  const int g = l >> 4, c = l & 15;
  const int w = tid >> 6, wr = w >> 1, wc = w & 1;
  const long m0 = (long)blockIdx.x*128, n0 = (long)blockIdx.y*128;
  __shared__ ushort_t lds_a[128*32];
  __shared__ ushort_t lds_b[128*32];
  f32x4 acc[4][4] = {};
  const int q1 = tid, q2 = 256 + tid;
  const ushort_t* a1 = A + (m0 + (q1>>2))*(long)K + (q1&3)*8;
  const ushort_t* a2 = A + (m0 + (q2>>2))*(long)K + (q2&3)*8;
  const ushort_t* b1 = B + (n0 + (q1>>2))*(long)K + (q1&3)*8;
  const ushort_t* b2 = B + (n0 + (q2>>2))*(long)K + (q2&3)*8;
  for (int k0 = 0; k0 < K; k0 += 32){
    __syncthreads();
    gload_lds16(a1 + k0, &lds_a[q1*8]);
    gload_lds16(a2 + k0, &lds_a[q2*8]);
    gload_lds16(b1 + k0, &lds_b[q1*8]);
    gload_lds16(b2 + k0, &lds_b[q2*8]);
    __syncthreads();
    short8 af[4], bf[4];
#pragma unroll
    for (int i = 0; i < 4; ++i) af[i] = *(const short8*)&lds_a[(wr*64 + i*16 + c)*32 + g*8];
#pragma unroll
    for (int j = 0; j < 4; ++j) bf[j] = *(const short8*)&lds_b[(wc*64 + j*16 + c)*32 + g*8];
#pragma unroll
    for (int i = 0; i < 4; ++i)
#pragma unroll
      for (int j = 0; j < 4; ++j)
        acc[i][j] = __builtin_amdgcn_mfma_f32_16x16x32_bf16(af[i], bf[j], acc[i][j], 0, 0, 0);
  }
#pragma unroll
  for (int i = 0; i < 4; ++i)
#pragma unroll
    for (int j = 0; j < 4; ++j)
#pragma unroll
      for (int r = 0; r < 4; ++r){
        long off = (m0 + wr*64 + i*16 + g*4 + r)*(long)N + n0 + wc*64 + j*16 + c;
        if constexpr (sizeof(CT) == 2) C[off] = (CT)f2bf(acc[i][j][r]);
        else                           C[off] = acc[i][j][r];
      }
}

// ---------------- flash attention: 4 waves, QBLK=64, KVBLK=64 ----------------
// K AND V double-buffered; ONE barrier per tile (prefetch issued at tile start,
// drained by the end-of-tile __syncthreads -> full-tile latency coverage).
// Swapped QK^T: s = mfma(K,Q) -> lane holds q-row = c, kv lane-local.
__global__ __launch_bounds__(256) void attn_kernel(const ushort_t* __restrict__ Q,
                                                   const ushort_t* __restrict__ Kr,
                                                   const ushort_t* __restrict__ Vt,
                                                   ushort_t* __restrict__ O){
  const int tid = threadIdx.x;
  const int l = tid & 63, w = tid >> 6;
  const int g = l >> 4, c = l & 15;
  const int bh = blockIdx.x;                          // x-fastest: heavy qt first across all bh
  const int qt = (int)gridDim.y - 1 - (int)blockIdx.y;
  const int b = bh >> 4, h = bh & 15;
  const int q0 = qt * 64;
  const int qw0 = q0 + w * 16;
  const int nt = qt + 1;

  __shared__ ushort_t k_lds[2][64*128];   // 2 x 16KB
  __shared__ ushort_t v_lds[2][128*64];   // 2 x 16KB
  __shared__ ushort_t p_lds[4][16*72];    // per-wave P

  short8 qf[4];
  const long qbase = ((long)(b*2048 + qw0 + c))*2048 + h*128 + g*8;
#pragma unroll
  for (int ds = 0; ds < 4; ++ds) qf[ds] = *(const short8*)(Q + qbase + ds*32);

  const ushort_t* ksrc[4]; const ushort_t* vsrc[4];
  int kof[4], vof[4];
#pragma unroll
  for (int i = 0; i < 4; ++i){
    int q = i*256 + tid;                 // 1024 chunks of 16B per tile
    int r = q >> 4, j = q & 15;
    ksrc[i] = Kr + ((long)(b*2048 + r))*2048 + h*128 + (j ^ (r & 7))*8;
    kof[i] = q*8;
    int d = q >> 3, jj = q & 7;
    vsrc[i] = Vt + ((long)(bh*128 + d))*2048 + (jj ^ (d & 7))*8;
    vof[i] = q*8;
  }

  f32x4 o[8] = {};
  float m = -1e30f, lsum = 0.f;
  const int sw = (c & 7) << 3;

  // prologue: stage tile 0 into buffer 0
#pragma unroll
  for (int i = 0; i < 4; ++i) gload_lds16(ksrc[i], &k_lds[0][kof[i]]);
#pragma unroll
  for (int i = 0; i < 4; ++i) gload_lds16(vsrc[i], &v_lds[0][vof[i]]);
  __syncthreads();

  for (int t = 0; t < nt; ++t){
    const int p = t & 1;
    // prefetch next tile into the other buffer (drained by end-of-tile barrier)
    if (t + 1 < nt){
#pragma unroll
      for (int i = 0; i < 4; ++i)
        gload_lds16(ksrc[i] + (long)(t+1)*64*2048, &k_lds[p^1][kof[i]]);
#pragma unroll
      for (int i = 0; i < 4; ++i)
        gload_lds16(vsrc[i] + (t+1)*64, &v_lds[p^1][vof[i]]);
    }
    const int kv0 = t*64;

    // ---- QK^T (swapped) ----
    f32x4 s[4] = {};
    __builtin_amdgcn_s_setprio(1);
#pragma unroll
    for (int t4 = 0; t4 < 4; ++t4){
      const int row = 16*t4 + c;
#pragma unroll
      for (int ds = 0; ds < 4; ++ds){
        short8 kf = *(const short8*)&k_lds[p][(row*128 + ds*32 + g*8) ^ sw];
        s[t4] = __builtin_amdgcn_mfma_f32_16x16x32_bf16(kf, qf[ds], s[t4], 0, 0, 0);
      }
    }
    __builtin_amdgcn_s_setprio(0);
    // ---- causal mask: q = qw0+c, kv = kv0+16t4+4g+r ----
    if (kv0 + 63 > qw0){
      const int qg = qw0 + c;
#pragma unroll
      for (int t4 = 0; t4 < 4; ++t4)
#pragma unroll
        for (int r = 0; r < 4; ++r)
          if (kv0 + 16*t4 + 4*g + r > qg) s[t4][r] = -1e30f;
    }
    // ---- per-lane online softmax (row = c) ----
    float tm = -1e30f;
#pragma unroll
    for (int t4 = 0; t4 < 4; ++t4)
      tm = fmaxf(tm, fmaxf(fmaxf(s[t4][0], s[t4][1]), fmaxf(s[t4][2], s[t4][3])));
    tm = fmaxf(tm, __shfl_xor(tm, 16, 64));
    tm = fmaxf(tm, __shfl_xor(tm, 32, 64));
    float mn = fmaxf(m, tm);
    float al = __expf(m - mn);
    float ps = 0.f;
#pragma unroll
    for (int t4 = 0; t4 < 4; ++t4)
#pragma unroll
      for (int r = 0; r < 4; ++r){ float pex = __expf(s[t4][r] - mn); s[t4][r] = pex; ps += pex; }
    ps += __shfl_xor(ps, 16, 64);
    ps += __shfl_xor(ps, 32, 64);
    lsum = lsum*al + ps;
    m = mn;
    float alr[4];
#pragma unroll
    for (int r = 0; r < 4; ++r) alr[r] = __shfl(al, 4*g + r, 64);
#pragma unroll
    for (int dt = 0; dt < 8; ++dt)
#pragma unroll
      for (int r = 0; r < 4; ++r) o[dt][r] *= alr[r];
    // ---- P write (wave-private, compiler orders ds_write->ds_read) ----
#pragma unroll
    for (int t4 = 0; t4 < 4; ++t4){
      uint2 pw;
      pw.x = (unsigned)f2bf(s[t4][0]) | ((unsigned)f2bf(s[t4][1]) << 16);
      pw.y = (unsigned)f2bf(s[t4][2]) | ((unsigned)f2bf(s[t4][3]) << 16);
      *reinterpret_cast<uint2*>(&p_lds[w][c*72 + 16*t4 + 4*g]) = pw;
    }
    // ---- PV ----
    __builtin_amdgcn_s_setprio(1);
#pragma unroll
    for (int kc = 0; kc < 2; ++kc){
      short8 pf = *(const short8*)&p_lds[w][c*72 + 32*kc + 8*g];
#pragma unroll
      for (int dt = 0; dt < 8; ++dt){
        short8 vf = *(const short8*)&v_lds[p][(((16*dt + c)*64) + kc*32 + g*8) ^ sw];
        o[dt] = __builtin_amdgcn_mfma_f32_16x16x32_bf16(pf, vf, o[dt], 0, 0, 0);
      }
    }
    __builtin_amdgcn_s_setprio(0);
    __syncthreads();   // drains prefetch; protects both dbl buffers for t+1
  }

  float inv = 1.f / lsum;
  float invr[4];
#pragma unroll
  for (int r = 0; r < 4; ++r) invr[r] = __shfl(inv, 4*g + r, 64);
  const long obase = ((long)(b*2048 + qw0 + g*4))*2048 + h*128 + c;
#pragma unroll
  for (int dt = 0; dt < 8; ++dt)
#pragma unroll
    for (int r = 0; r < 4; ++r)
      O[obase + (long)r*2048 + dt*16] = f2bf(o[dt][r] * invr[r]);
}

// ---------------- launcher ----------------
extern "C" void kernel_launch(void* const* d_in, const int* in_sizes, int n_in,
                              void* d_out, int out_size, void* d_ws, size_t ws_size,
                              hipStream_t stream){
  const float* x    = (const float*)d_in[0];
  const float* cosb = (const float*)d_in[1];
  const float* sinb = (const float*)d_in[2];
  const float* wq   = (const float*)d_in[3];
  const float* wk   = (const float*)d_in[4];
  const float* wv   = (const float*)d_in[5];
  const float* wo   = (const float*)d_in[6];
  float* out = (float*)d_out;

  const int S = 2048, DIM = 2048;
  const long MN = 4096;

  char* ws = (char*)d_ws;
  ushort_t* xb    = (ushort_t*)(ws);                 // 16MB
  ushort_t* wqb   = (ushort_t*)(ws + (16l<<20));
  ushort_t* wkb   = (ushort_t*)(ws + (24l<<20));
  ushort_t* wvb   = (ushort_t*)(ws + (32l<<20));
  ushort_t* wob   = (ushort_t*)(ws + (40l<<20));
  ushort_t* stage = (ushort_t*)(ws + (48l<<20));     // 16MB bf16
  ushort_t* attnb = (ushort_t*)(ws + (64l<<20));     // 16MB
  ushort_t* qr    = (ushort_t*)(ws + (80l<<20));
  ushort_t* kr    = (ushort_t*)(ws + (96l<<20));
  ushort_t* vt    = (ushort_t*)(ws + (112l<<20));

  const long xn4 = MN*DIM/4, wn4 = (long)DIM*DIM/4;
  cast_bf16_kernel<<<(int)((xn4+255)/256), 256, 0, stream>>>(x, xb, xn4);
  cast4_bf16_kernel<<<dim3((int)((wn4+255)/256), 4), 256, 0, stream>>>(
      wq, wk, wv, wo, wqb, wkb, wvb, wob, wn4);

  dim3 ggrid(MN/128, DIM/128);
  const int ropeBlocks = (2*2048*16*16)/256;

  gemm_nt_lds<ushort_t><<<ggrid, 256, 0, stream>>>(xb, wqb, stage, (int)MN, DIM, DIM);
  rope_kernel<<<ropeBlocks, 256, 0, stream>>>(stage, cosb, sinb, qr, 0.08838834764831845f);
  gemm_nt_lds<ushort_t><<<ggrid, 256, 0, stream>>>(xb, wkb, stage, (int)MN, DIM, DIM);
  rope_kernel<<<ropeBlocks, 256, 0, stream>>>(stage, cosb, sinb, kr, 1.0f);
  gemm_nt_lds<ushort_t><<<ggrid, 256, 0, stream>>>(xb, wvb, stage, (int)MN, DIM, DIM);
  vt_kernel<<<dim3(S/64, 32), 256, 0, stream>>>(stage, vt);
  attn_kernel<<<dim3(32, S/64), 256, 0, stream>>>(qr, kr, vt, attnb);
  gemm_nt_lds<float><<<ggrid, 256, 0, stream>>>(attnb, wob, out, (int)MN, DIM, DIM);
}

// Round 6
// 304.281 us; speedup vs baseline: 2.9031x; 1.0872x over previous
//
#include <hip/hip_runtime.h>

typedef short short8 __attribute__((ext_vector_type(8)));
typedef float f32x4 __attribute__((ext_vector_type(4)));
typedef unsigned short ushort_t;

__device__ __forceinline__ unsigned short f2bf(float f){
  unsigned int u = __builtin_bit_cast(unsigned int, f);
  u += 0x7FFFu + ((u >> 16) & 1u);
  return (unsigned short)(u >> 16);
}
__device__ __forceinline__ float bf2f(unsigned short u){
  return __builtin_bit_cast(float, ((unsigned int)u) << 16);
}
__device__ __forceinline__ void gload_lds16(const void* g, void* l){
  __builtin_amdgcn_global_load_lds((const __attribute__((address_space(1))) unsigned int*)g,
                                   (__attribute__((address_space(3))) unsigned int*)l, 16, 0, 0);
}

// ---------------- elementwise casts ----------------
__global__ __launch_bounds__(256) void cast_bf16_kernel(const float* __restrict__ in,
                                                        ushort_t* __restrict__ out, long n4){
  long i = (long)blockIdx.x*256 + threadIdx.x;
  if (i >= n4) return;
  const float4 v = reinterpret_cast<const float4*>(in)[i];
  ushort4 o; o.x=f2bf(v.x); o.y=f2bf(v.y); o.z=f2bf(v.z); o.w=f2bf(v.w);
  reinterpret_cast<ushort4*>(out)[i] = o;
}

__global__ __launch_bounds__(256) void cast4_bf16_kernel(const float* __restrict__ w0, const float* __restrict__ w1,
                                                         const float* __restrict__ w2, const float* __restrict__ w3,
                                                         ushort_t* __restrict__ o0, ushort_t* __restrict__ o1,
                                                         ushort_t* __restrict__ o2, ushort_t* __restrict__ o3,
                                                         long n4){
  long i = (long)blockIdx.x*256 + threadIdx.x;
  if (i >= n4) return;
  const float* in; ushort_t* out;
  switch (blockIdx.y){
    case 0: in = w0; out = o0; break;
    case 1: in = w1; out = o1; break;
    case 2: in = w2; out = o2; break;
    default: in = w3; out = o3; break;
  }
  const float4 v = reinterpret_cast<const float4*>(in)[i];
  ushort4 o; o.x=f2bf(v.x); o.y=f2bf(v.y); o.z=f2bf(v.z); o.w=f2bf(v.w);
  reinterpret_cast<ushort4*>(out)[i] = o;
}

// ---------------- in-place RoPE on bf16 (Q and K in one dispatch) ----------------
__global__ __launch_bounds__(256) void rope2_kernel(ushort_t* __restrict__ Qs,
                                                    ushort_t* __restrict__ Ks,
                                                    const float* __restrict__ cosb,
                                                    const float* __restrict__ sinb){
  long idx = (long)blockIdx.x*256 + threadIdx.x;    // B*S*H*16 threads
  ushort_t* X = blockIdx.y ? Ks : Qs;
  const float scale = blockIdx.y ? 1.0f : 0.08838834764831845f;
  int dq = (int)(idx & 15);
  long rest = idx >> 4;
  int h = (int)(rest & 15); rest >>= 4;
  int s = (int)(rest & 2047);
  int b = (int)(rest >> 11);
  long base = ((long)(b*2048 + s))*2048 + h*128;
  int d0 = dq*4;
  ushort4 x1 = *(const ushort4*)&X[base + d0];
  ushort4 x2 = *(const ushort4*)&X[base + 64 + d0];
  float4 cc = *(const float4*)&cosb[s*64 + d0];
  float4 ss = *(const float4*)&sinb[s*64 + d0];
  ushort4 o1, o2;
  { float a=bf2f(x1.x), bb=bf2f(x2.x); o1.x=f2bf((a*cc.x-bb*ss.x)*scale); o2.x=f2bf((a*ss.x+bb*cc.x)*scale); }
  { float a=bf2f(x1.y), bb=bf2f(x2.y); o1.y=f2bf((a*cc.y-bb*ss.y)*scale); o2.y=f2bf((a*ss.y+bb*cc.y)*scale); }
  { float a=bf2f(x1.z), bb=bf2f(x2.z); o1.z=f2bf((a*cc.z-bb*ss.z)*scale); o2.z=f2bf((a*ss.z+bb*cc.z)*scale); }
  { float a=bf2f(x1.w), bb=bf2f(x2.w); o1.w=f2bf((a*cc.w-bb*ss.w)*scale); o2.w=f2bf((a*ss.w+bb*cc.w)*scale); }
  *(ushort4*)&X[base + d0] = o1;
  *(ushort4*)&X[base + 64 + d0] = o2;
}

// ---------------- V transpose (bf16 in) to (B*H, Dh, S) ----------------
__global__ __launch_bounds__(256) void vt_kernel(const ushort_t* __restrict__ vf,
                                                 ushort_t* __restrict__ vt){
  const int s0 = blockIdx.x*64;
  const int bh = blockIdx.y;
  const int b = bh >> 4, h = bh & 15;
  const int tid = threadIdx.x;
  __shared__ ushort_t tile[128][72];
#pragma unroll
  for (int i = 0; i < 4; ++i){
    int q = i*256 + tid;
    int sl = q >> 4, dc = (q & 15)*8;
    short8 v = *(const short8*)&vf[((long)(b*2048 + s0 + sl))*2048 + h*128 + dc];
#pragma unroll
    for (int k = 0; k < 8; ++k) tile[dc + k][sl] = (ushort_t)v[k];
  }
  __syncthreads();
#pragma unroll
  for (int i = 0; i < 4; ++i){
    int q = i*256 + tid;
    int d = q >> 3, sc = (q & 7)*8;
    *(short8*)&vt[((long)(bh*128 + d))*2048 + s0 + sc] = *(const short8*)&tile[d][sc];
  }
}

// ================= 8-phase 256x256 NT GEMM (QKV fused) =================
// C = A[M][K] @ B[N][K]^T, bf16. Output split into 3 matrices of 2048 cols
// (stride 8M elems). 512 thr = 8 waves (2M x 4N); BK=64; 2 K-tiles/iter;
// 8 phases/iter; counted vmcnt(4); XOR slot swizzle (slot ^= row&7).

#define LDA8(P, QM) do{ \
  _Pragma("unroll") for (int i_ = 0; i_ < 4; ++i_){ \
    af[i_][0] = *(const short8*)&lA[(P)*16384 + ((QM)*128 + aRowBase + i_*16)*64 + sw0]; \
    af[i_][1] = *(const short8*)&lA[(P)*16384 + ((QM)*128 + aRowBase + i_*16)*64 + sw1]; } }while(0)

#define LDB4(P, QN) do{ \
  _Pragma("unroll") for (int j_ = 0; j_ < 2; ++j_){ \
    bfr[j_][0] = *(const short8*)&lB[(P)*16384 + ((QN)*128 + bRowBase + j_*16)*64 + sw0]; \
    bfr[j_][1] = *(const short8*)&lB[(P)*16384 + ((QN)*128 + bRowBase + j_*16)*64 + sw1]; } }while(0)

#define STAGE_A(P, QM, T) do{ \
  gload_lds16(aS0 + (long)(QM)*64*K + (long)(T)*64, &lA[(P)*16384 + (QM)*8192 + tid*8]); \
  gload_lds16(aS1 + (long)(QM)*64*K + (long)(T)*64, &lA[(P)*16384 + (QM)*8192 + 4096 + tid*8]); }while(0)

#define STAGE_B(P, QN, T) do{ \
  gload_lds16(bS0 + (long)(QN)*32*K + (long)(T)*64, &lB[(P)*16384 + (QN)*8192 + tid*8]); \
  gload_lds16(bS1 + (long)(QN)*32*K + (long)(T)*64, &lB[(P)*16384 + (QN)*8192 + 4096 + tid*8]); }while(0)

#define MF16(QM, QN) do{ \
  __builtin_amdgcn_s_setprio(1); \
  _Pragma("unroll") for (int i_ = 0; i_ < 4; ++i_){ \
    _Pragma("unroll") for (int j_ = 0; j_ < 2; ++j_){ \
      acc[(QM)*4+i_][(QN)*2+j_] = __builtin_amdgcn_mfma_f32_16x16x32_bf16(af[i_][0], bfr[j_][0], acc[(QM)*4+i_][(QN)*2+j_], 0, 0, 0); \
      acc[(QM)*4+i_][(QN)*2+j_] = __builtin_amdgcn_mfma_f32_16x16x32_bf16(af[i_][1], bfr[j_][1], acc[(QM)*4+i_][(QN)*2+j_], 0, 0, 0); } } \
  __builtin_amdgcn_s_setprio(0); }while(0)

#define WAITC(MORE) do{ \
  if (MORE) asm volatile("s_waitcnt vmcnt(4)" ::: "memory"); \
  else      asm volatile("s_waitcnt vmcnt(0)" ::: "memory"); }while(0)

#define PH(P, QM, QN, STG, WT) do{ \
  if ((QN) == 0) { LDA8(P, QM); } \
  LDB4(P, QN); \
  STG; \
  WT; \
  __builtin_amdgcn_s_barrier(); \
  asm volatile("" ::: "memory"); \
  MF16(QM, QN); \
  __builtin_amdgcn_s_barrier(); \
  asm volatile("" ::: "memory"); }while(0)

__global__ __launch_bounds__(512, 2) void gemm_qkv_8ph(const ushort_t* __restrict__ A,
                                                       const ushort_t* __restrict__ Bw,
                                                       ushort_t* __restrict__ Cq,
                                                       int MT, int K){
  __shared__ ushort_t lA[32768];   // [2 buf][128KB total with lB]
  __shared__ ushort_t lB[32768];
  const int tid = threadIdx.x;
  const int lane = tid & 63, wid = tid >> 6;
  const int g = lane >> 4, c = lane & 15;
  const int wm = wid >> 2, wn = wid & 3;

  // XCD-aware bijective swizzle (nwg % 8 == 0), column-major tiles for B reuse
  const int nwg = (int)gridDim.x, cpx = nwg >> 3;
  int sw = (blockIdx.x & 7)*cpx + (blockIdx.x >> 3);
  const long m0 = (long)(sw % MT)*256;
  const long n0 = (long)(sw / MT)*256;

  // staging source bases (pre-inverse-swizzled slots)
  const int prl0 = tid >> 3, q1 = 512 + tid, prl1 = q1 >> 3;
  const int sl0 = ((tid & 7) ^ (prl0 & 7)) * 8;
  const int sl1 = ((q1 & 7) ^ (prl1 & 7)) * 8;
  const int rowA0 = ((prl0 >> 6)*128) + (prl0 & 63);
  const int rowA1 = ((prl1 >> 6)*128) + (prl1 & 63);
  const int rowB0 = ((prl0 >> 5)*64) + (prl0 & 31);
  const int rowB1 = ((prl1 >> 5)*64) + (prl1 & 31);
  const ushort_t* aS0 = A + (m0 + rowA0)*K + sl0;
  const ushort_t* aS1 = A + (m0 + rowA1)*K + sl1;
  const ushort_t* bS0 = Bw + (n0 + rowB0)*K + sl0;
  const ushort_t* bS1 = Bw + (n0 + rowB1)*K + sl1;

  // fragment read constants
  const int sw0 = (g ^ (c & 7)) * 8;
  const int sw1 = ((4 + g) ^ (c & 7)) * 8;
  const int aRowBase = wm*64 + c;
  const int bRowBase = wn*32 + c;

  f32x4 acc[8][4] = {};
  short8 af[4][2], bfr[2][2];
  const int NI = K >> 7;   // iterations (2 K-tiles each)

  // prologue: stage t0 fully + t1.A0 + t1.B0
  STAGE_A(0, 0, 0); STAGE_B(0, 0, 0);
  STAGE_A(0, 1, 0); STAGE_B(0, 1, 0);
  STAGE_A(1, 0, 1); STAGE_B(1, 0, 1);
  asm volatile("s_waitcnt vmcnt(4)" ::: "memory");
  __builtin_amdgcn_s_barrier();
  asm volatile("" ::: "memory");

  for (int j = 0; j < NI; ++j){
    const int t = 2*j;
    const bool more = (j + 1 < NI);
    PH(0, 0, 0, STAGE_A(1, 1, t+1), ((void)0));
    PH(0, 0, 1, STAGE_B(1, 1, t+1), ((void)0));
    PH(0, 1, 0, if(more){STAGE_A(0, 0, t+2);}, ((void)0));
    PH(0, 1, 1, if(more){STAGE_B(0, 0, t+2);}, WAITC(more));
    PH(1, 0, 0, if(more){STAGE_A(0, 1, t+2);}, ((void)0));
    PH(1, 0, 1, if(more){STAGE_B(0, 1, t+2);}, ((void)0));
    PH(1, 1, 0, if(more){STAGE_A(1, 0, t+3);}, ((void)0));
    PH(1, 1, 1, if(more){STAGE_B(1, 0, t+3);}, WAITC(more));
  }

  // epilogue: C split into 3 matrices of 2048 cols, stride 8M elems
  const long rbase = m0 + wm*128 + g*4;
  const long cbase = n0 + wn*64 + c;
#pragma unroll
  for (int mi = 0; mi < 8; ++mi)
#pragma unroll
    for (int ni = 0; ni < 4; ++ni){
      long col6 = cbase + ni*16;
      long off = (long)(col6 >> 11)*8388608 + (rbase + mi*16)*2048 + (col6 & 2047);
#pragma unroll
      for (int r = 0; r < 4; ++r)
        Cq[off + (long)r*2048] = f2bf(acc[mi][ni][r]);
    }
}

// ---------------- m97-style NT GEMM (used for WO): C f32 ----------------
__global__ __launch_bounds__(256) void gemm_nt_lds(const ushort_t* __restrict__ A,
                                                   const ushort_t* __restrict__ B,
                                                   float* __restrict__ C,
                                                   int M, int N, int K){
  const int tid = threadIdx.x;
  const int l = tid & 63;
  const int g = l >> 4, c = l & 15;
  const int w = tid >> 6, wr = w >> 1, wc = w & 1;
  const long m0 = (long)blockIdx.x*128, n0 = (long)blockIdx.y*128;
  __shared__ ushort_t lds_a[128*32];
  __shared__ ushort_t lds_b[128*32];
  f32x4 acc[4][4] = {};
  const int q1 = tid, q2 = 256 + tid;
  const ushort_t* a1 = A + (m0 + (q1>>2))*(long)K + (q1&3)*8;
  const ushort_t* a2 = A + (m0 + (q2>>2))*(long)K + (q2&3)*8;
  const ushort_t* b1 = B + (n0 + (q1>>2))*(long)K + (q1&3)*8;
  const ushort_t* b2 = B + (n0 + (q2>>2))*(long)K + (q2&3)*8;
  for (int k0 = 0; k0 < K; k0 += 32){
    __syncthreads();
    gload_lds16(a1 + k0, &lds_a[q1*8]);
    gload_lds16(a2 + k0, &lds_a[q2*8]);
    gload_lds16(b1 + k0, &lds_b[q1*8]);
    gload_lds16(b2 + k0, &lds_b[q2*8]);
    __syncthreads();
    short8 af[4], bf[4];
#pragma unroll
    for (int i = 0; i < 4; ++i) af[i] = *(const short8*)&lds_a[(wr*64 + i*16 + c)*32 + g*8];
#pragma unroll
    for (int j = 0; j < 4; ++j) bf[j] = *(const short8*)&lds_b[(wc*64 + j*16 + c)*32 + g*8];
#pragma unroll
    for (int i = 0; i < 4; ++i)
#pragma unroll
      for (int j = 0; j < 4; ++j)
        acc[i][j] = __builtin_amdgcn_mfma_f32_16x16x32_bf16(af[i], bf[j], acc[i][j], 0, 0, 0);
  }
#pragma unroll
  for (int i = 0; i < 4; ++i)
#pragma unroll
    for (int j = 0; j < 4; ++j)
#pragma unroll
      for (int r = 0; r < 4; ++r)
        C[(m0 + wr*64 + i*16 + g*4 + r)*(long)N + n0 + wc*64 + j*16 + c] = acc[i][j][r];
}

// ---------------- flash attention (round-5 structure + defer-max) ----------------
__global__ __launch_bounds__(256) void attn_kernel(const ushort_t* __restrict__ Q,
                                                   const ushort_t* __restrict__ Kr,
                                                   const ushort_t* __restrict__ Vt,
                                                   ushort_t* __restrict__ O){
  const int tid = threadIdx.x;
  const int l = tid & 63, w = tid >> 6;
  const int g = l >> 4, c = l & 15;
  const int bh = blockIdx.x;
  const int qt = (int)gridDim.y - 1 - (int)blockIdx.y;
  const int b = bh >> 4, h = bh & 15;
  const int q0 = qt * 64;
  const int qw0 = q0 + w * 16;
  const int nt = qt + 1;

  __shared__ ushort_t k_lds[2][64*128];
  __shared__ ushort_t v_lds[2][128*64];
  __shared__ ushort_t p_lds[4][16*72];

  short8 qf[4];
  const long qbase = ((long)(b*2048 + qw0 + c))*2048 + h*128 + g*8;
#pragma unroll
  for (int ds = 0; ds < 4; ++ds) qf[ds] = *(const short8*)(Q + qbase + ds*32);

  const ushort_t* ksrc[4]; const ushort_t* vsrc[4];
  int kof[4], vof[4];
#pragma unroll
  for (int i = 0; i < 4; ++i){
    int q = i*256 + tid;
    int r = q >> 4, j = q & 15;
    ksrc[i] = Kr + ((long)(b*2048 + r))*2048 + h*128 + (j ^ (r & 7))*8;
    kof[i] = q*8;
    int d = q >> 3, jj = q & 7;
    vsrc[i] = Vt + ((long)(bh*128 + d))*2048 + (jj ^ (d & 7))*8;
    vof[i] = q*8;
  }

  f32x4 o[8] = {};
  float m = -1e30f, lsum = 0.f;
  const int sw = (c & 7) << 3;

#pragma unroll
  for (int i = 0; i < 4; ++i) gload_lds16(ksrc[i], &k_lds[0][kof[i]]);
#pragma unroll
  for (int i = 0; i < 4; ++i) gload_lds16(vsrc[i], &v_lds[0][vof[i]]);
  __syncthreads();

  for (int t = 0; t < nt; ++t){
    const int p = t & 1;
    if (t + 1 < nt){
#pragma unroll
      for (int i = 0; i < 4; ++i)
        gload_lds16(ksrc[i] + (long)(t+1)*64*2048, &k_lds[p^1][kof[i]]);
#pragma unroll
      for (int i = 0; i < 4; ++i)
        gload_lds16(vsrc[i] + (t+1)*64, &v_lds[p^1][vof[i]]);
    }
    const int kv0 = t*64;

    f32x4 s[4] = {};
    __builtin_amdgcn_s_setprio(1);
#pragma unroll
    for (int t4 = 0; t4 < 4; ++t4){
      const int row = 16*t4 + c;
#pragma unroll
      for (int ds = 0; ds < 4; ++ds){
        short8 kf = *(const short8*)&k_lds[p][(row*128 + ds*32 + g*8) ^ sw];
        s[t4] = __builtin_amdgcn_mfma_f32_16x16x32_bf16(kf, qf[ds], s[t4], 0, 0, 0);
      }
    }
    __builtin_amdgcn_s_setprio(0);
    if (kv0 + 63 > qw0){
      const int qg = qw0 + c;
#pragma unroll
      for (int t4 = 0; t4 < 4; ++t4)
#pragma unroll
        for (int r = 0; r < 4; ++r)
          if (kv0 + 16*t4 + 4*g + r > qg) s[t4][r] = -1e30f;
    }
    // ---- per-lane online softmax with defer-max (T13, THR=8) ----
    float tm = -1e30f;
#pragma unroll
    for (int t4 = 0; t4 < 4; ++t4)
      tm = fmaxf(tm, fmaxf(fmaxf(s[t4][0], s[t4][1]), fmaxf(s[t4][2], s[t4][3])));
    tm = fmaxf(tm, __shfl_xor(tm, 16, 64));
    tm = fmaxf(tm, __shfl_xor(tm, 32, 64));
    if (!__all(tm <= m + 8.f)){
      float mn = fmaxf(m, tm);
      float al = __expf(m - mn);
      m = mn;
      lsum *= al;
      float alr[4];
#pragma unroll
      for (int r = 0; r < 4; ++r) alr[r] = __shfl(al, 4*g + r, 64);
#pragma unroll
      for (int dt = 0; dt < 8; ++dt)
#pragma unroll
        for (int r = 0; r < 4; ++r) o[dt][r] *= alr[r];
    }
    float ps = 0.f;
#pragma unroll
    for (int t4 = 0; t4 < 4; ++t4)
#pragma unroll
      for (int r = 0; r < 4; ++r){ float pex = __expf(s[t4][r] - m); s[t4][r] = pex; ps += pex; }
    ps += __shfl_xor(ps, 16, 64);
    ps += __shfl_xor(ps, 32, 64);
    lsum += ps;
#pragma unroll
    for (int t4 = 0; t4 < 4; ++t4){
      uint2 pw;
      pw.x = (unsigned)f2bf(s[t4][0]) | ((unsigned)f2bf(s[t4][1]) << 16);
      pw.y = (unsigned)f2bf(s[t4][2]) | ((unsigned)f2bf(s[t4][3]) << 16);
      *reinterpret_cast<uint2*>(&p_lds[w][c*72 + 16*t4 + 4*g]) = pw;
    }
    __builtin_amdgcn_s_setprio(1);
#pragma unroll
    for (int kc = 0; kc < 2; ++kc){
      short8 pf = *(const short8*)&p_lds[w][c*72 + 32*kc + 8*g];
#pragma unroll
      for (int dt = 0; dt < 8; ++dt){
        short8 vf = *(const short8*)&v_lds[p][(((16*dt + c)*64) + kc*32 + g*8) ^ sw];
        o[dt] = __builtin_amdgcn_mfma_f32_16x16x32_bf16(pf, vf, o[dt], 0, 0, 0);
      }
    }
    __builtin_amdgcn_s_setprio(0);
    __syncthreads();
  }

  float inv = 1.f / lsum;
  float invr[4];
#pragma unroll
  for (int r = 0; r < 4; ++r) invr[r] = __shfl(inv, 4*g + r, 64);
  const long obase = ((long)(b*2048 + qw0 + g*4))*2048 + h*128 + c;
#pragma unroll
  for (int dt = 0; dt < 8; ++dt)
#pragma unroll
    for (int r = 0; r < 4; ++r)
      O[obase + (long)r*2048 + dt*16] = f2bf(o[dt][r] * invr[r]);
}

// ---------------- launcher ----------------
extern "C" void kernel_launch(void* const* d_in, const int* in_sizes, int n_in,
                              void* d_out, int out_size, void* d_ws, size_t ws_size,
                              hipStream_t stream){
  const float* x    = (const float*)d_in[0];
  const float* cosb = (const float*)d_in[1];
  const float* sinb = (const float*)d_in[2];
  const float* wq   = (const float*)d_in[3];
  const float* wk   = (const float*)d_in[4];
  const float* wv   = (const float*)d_in[5];
  const float* wo   = (const float*)d_in[6];
  float* out = (float*)d_out;

  const int S = 2048, DIM = 2048;
  const long MN = 4096;

  char* ws = (char*)d_ws;
  ushort_t* xb     = (ushort_t*)(ws);                 // 16MB
  ushort_t* wqkvb  = (ushort_t*)(ws + (16l<<20));     // 24MB [6144][2048]
  ushort_t* wob    = (ushort_t*)(ws + (40l<<20));     // 8MB
  ushort_t* qstage = (ushort_t*)(ws + (48l<<20));     // 16MB (rope in-place)
  ushort_t* kstage = (ushort_t*)(ws + (64l<<20));     // 16MB
  ushort_t* vstage = (ushort_t*)(ws + (80l<<20));     // 16MB (attnb aliases)
  ushort_t* vt     = (ushort_t*)(ws + (96l<<20));     // 16MB -> 112MB total
  ushort_t* attnb  = vstage;

  const long xn4 = MN*DIM/4, wn4 = (long)DIM*DIM/4;
  cast_bf16_kernel<<<(int)((xn4+255)/256), 256, 0, stream>>>(x, xb, xn4);
  cast4_bf16_kernel<<<dim3((int)((wn4+255)/256), 4), 256, 0, stream>>>(
      wq, wk, wv, wo,
      wqkvb, wqkvb + 4194304, wqkvb + 8388608, wob, wn4);

  // fused QKV projection: [4096][6144] -> qstage/kstage/vstage
  gemm_qkv_8ph<<<(MN/256)*(6144/256), 512, 0, stream>>>(xb, wqkvb, qstage, (int)(MN/256), DIM);

  const int ropeBlocks = (2*2048*16*16)/256;
  rope2_kernel<<<dim3(ropeBlocks, 2), 256, 0, stream>>>(qstage, kstage, cosb, sinb);
  vt_kernel<<<dim3(S/64, 32), 256, 0, stream>>>(vstage, vt);
  attn_kernel<<<dim3(32, S/64), 256, 0, stream>>>(qstage, kstage, vt, attnb);
  gemm_nt_lds<<<dim3(MN/128, DIM/128), 256, 0, stream>>>(attnb, wob, out, (int)MN, DIM, DIM);
}

// Round 7
// 298.867 us; speedup vs baseline: 2.9557x; 1.0181x over previous
//
#include <hip/hip_runtime.h>

typedef short short8 __attribute__((ext_vector_type(8)));
typedef float f32x4 __attribute__((ext_vector_type(4)));
typedef unsigned short ushort_t;

__device__ __forceinline__ unsigned short f2bf(float f){
  unsigned int u = __builtin_bit_cast(unsigned int, f);
  u += 0x7FFFu + ((u >> 16) & 1u);
  return (unsigned short)(u >> 16);
}
__device__ __forceinline__ float bf2f(unsigned short u){
  return __builtin_bit_cast(float, ((unsigned int)u) << 16);
}
__device__ __forceinline__ void gload_lds16(const void* g, void* l){
  __builtin_amdgcn_global_load_lds((const __attribute__((address_space(1))) unsigned int*)g,
                                   (__attribute__((address_space(3))) unsigned int*)l, 16, 0, 0);
}

// ---------------- elementwise casts ----------------
__global__ __launch_bounds__(256) void cast_bf16_kernel(const float* __restrict__ in,
                                                        ushort_t* __restrict__ out, long n4){
  long i = (long)blockIdx.x*256 + threadIdx.x;
  if (i >= n4) return;
  const float4 v = reinterpret_cast<const float4*>(in)[i];
  ushort4 o; o.x=f2bf(v.x); o.y=f2bf(v.y); o.z=f2bf(v.z); o.w=f2bf(v.w);
  reinterpret_cast<ushort4*>(out)[i] = o;
}

__global__ __launch_bounds__(256) void cast4_bf16_kernel(const float* __restrict__ w0, const float* __restrict__ w1,
                                                         const float* __restrict__ w2, const float* __restrict__ w3,
                                                         ushort_t* __restrict__ o0, ushort_t* __restrict__ o1,
                                                         ushort_t* __restrict__ o2, ushort_t* __restrict__ o3,
                                                         long n4){
  long i = (long)blockIdx.x*256 + threadIdx.x;
  if (i >= n4) return;
  const float* in; ushort_t* out;
  switch (blockIdx.y){
    case 0: in = w0; out = o0; break;
    case 1: in = w1; out = o1; break;
    case 2: in = w2; out = o2; break;
    default: in = w3; out = o3; break;
  }
  const float4 v = reinterpret_cast<const float4*>(in)[i];
  ushort4 o; o.x=f2bf(v.x); o.y=f2bf(v.y); o.z=f2bf(v.z); o.w=f2bf(v.w);
  reinterpret_cast<ushort4*>(out)[i] = o;
}

// ---------------- in-place RoPE on bf16 (Q and K in one dispatch) ----------------
__global__ __launch_bounds__(256) void rope2_kernel(ushort_t* __restrict__ Qs,
                                                    ushort_t* __restrict__ Ks,
                                                    const float* __restrict__ cosb,
                                                    const float* __restrict__ sinb){
  long idx = (long)blockIdx.x*256 + threadIdx.x;    // B*S*H*16 threads
  ushort_t* X = blockIdx.y ? Ks : Qs;
  const float scale = blockIdx.y ? 1.0f : 0.08838834764831845f;
  int dq = (int)(idx & 15);
  long rest = idx >> 4;
  int h = (int)(rest & 15); rest >>= 4;
  int s = (int)(rest & 2047);
  int b = (int)(rest >> 11);
  long base = ((long)(b*2048 + s))*2048 + h*128;
  int d0 = dq*4;
  ushort4 x1 = *(const ushort4*)&X[base + d0];
  ushort4 x2 = *(const ushort4*)&X[base + 64 + d0];
  float4 cc = *(const float4*)&cosb[s*64 + d0];
  float4 ss = *(const float4*)&sinb[s*64 + d0];
  ushort4 o1, o2;
  { float a=bf2f(x1.x), bb=bf2f(x2.x); o1.x=f2bf((a*cc.x-bb*ss.x)*scale); o2.x=f2bf((a*ss.x+bb*cc.x)*scale); }
  { float a=bf2f(x1.y), bb=bf2f(x2.y); o1.y=f2bf((a*cc.y-bb*ss.y)*scale); o2.y=f2bf((a*ss.y+bb*cc.y)*scale); }
  { float a=bf2f(x1.z), bb=bf2f(x2.z); o1.z=f2bf((a*cc.z-bb*ss.z)*scale); o2.z=f2bf((a*ss.z+bb*cc.z)*scale); }
  { float a=bf2f(x1.w), bb=bf2f(x2.w); o1.w=f2bf((a*cc.w-bb*ss.w)*scale); o2.w=f2bf((a*ss.w+bb*cc.w)*scale); }
  *(ushort4*)&X[base + d0] = o1;
  *(ushort4*)&X[base + 64 + d0] = o2;
}

// ================= 8-phase 256x256 NT GEMM, QKV fused =================
// C = A[M][K] @ B[N][K]^T bf16. Q,K thirds -> row-major [4096][2048];
// V third -> written TRANSPOSED directly to Vt[(bh*128+d)][s].
// 512 thr = 8 waves (2M x 4N); BK=64; 2 K-tiles/iter; 8 phases/iter;
// counted vmcnt(4); XOR slot swizzle; MFMA k-outermost (8-indep runs).

#define LDA8(P, QM) do{ \
  _Pragma("unroll") for (int i_ = 0; i_ < 4; ++i_){ \
    af[i_][0] = *(const short8*)&lA[(P)*16384 + ((QM)*128 + aRowBase + i_*16)*64 + sw0]; \
    af[i_][1] = *(const short8*)&lA[(P)*16384 + ((QM)*128 + aRowBase + i_*16)*64 + sw1]; } }while(0)

#define LDB4(P, QN) do{ \
  _Pragma("unroll") for (int j_ = 0; j_ < 2; ++j_){ \
    bfr[j_][0] = *(const short8*)&lB[(P)*16384 + ((QN)*128 + bRowBase + j_*16)*64 + sw0]; \
    bfr[j_][1] = *(const short8*)&lB[(P)*16384 + ((QN)*128 + bRowBase + j_*16)*64 + sw1]; } }while(0)

#define STAGE_A(P, QM, T) do{ \
  gload_lds16(aS0 + (long)(QM)*64*K + (long)(T)*64, &lA[(P)*16384 + (QM)*8192 + tid*8]); \
  gload_lds16(aS1 + (long)(QM)*64*K + (long)(T)*64, &lA[(P)*16384 + (QM)*8192 + 4096 + tid*8]); }while(0)

#define STAGE_B(P, QN, T) do{ \
  gload_lds16(bS0 + (long)(QN)*32*K + (long)(T)*64, &lB[(P)*16384 + (QN)*8192 + tid*8]); \
  gload_lds16(bS1 + (long)(QN)*32*K + (long)(T)*64, &lB[(P)*16384 + (QN)*8192 + 4096 + tid*8]); }while(0)

#define MF16(QM, QN) do{ \
  __builtin_amdgcn_s_setprio(1); \
  _Pragma("unroll") for (int k_ = 0; k_ < 2; ++k_) \
    _Pragma("unroll") for (int i_ = 0; i_ < 4; ++i_) \
      _Pragma("unroll") for (int j_ = 0; j_ < 2; ++j_) \
        acc[(QM)*4+i_][(QN)*2+j_] = __builtin_amdgcn_mfma_f32_16x16x32_bf16(af[i_][k_], bfr[j_][k_], acc[(QM)*4+i_][(QN)*2+j_], 0, 0, 0); \
  __builtin_amdgcn_s_setprio(0); }while(0)

#define WAITC(MORE) do{ \
  if (MORE) asm volatile("s_waitcnt vmcnt(4)" ::: "memory"); \
  else      asm volatile("s_waitcnt vmcnt(0)" ::: "memory"); }while(0)

#define PH(P, QM, QN, STG, WT) do{ \
  if ((QN) == 0) { LDA8(P, QM); } \
  LDB4(P, QN); \
  STG; \
  WT; \
  __builtin_amdgcn_s_barrier(); \
  asm volatile("" ::: "memory"); \
  MF16(QM, QN); \
  __builtin_amdgcn_s_barrier(); \
  asm volatile("" ::: "memory"); }while(0)

__global__ __launch_bounds__(512, 2) void gemm_qkv_8ph(const ushort_t* __restrict__ A,
                                                       const ushort_t* __restrict__ Bw,
                                                       ushort_t* __restrict__ Cq,
                                                       ushort_t* __restrict__ Ck,
                                                       ushort_t* __restrict__ Vt,
                                                       int MT, int K){
  __shared__ ushort_t lA[32768];
  __shared__ ushort_t lB[32768];
  const int tid = threadIdx.x;
  const int lane = tid & 63, wid = tid >> 6;
  const int g = lane >> 4, c = lane & 15;
  const int wm = wid >> 2, wn = wid & 3;

  const int nwg = (int)gridDim.x, cpx = nwg >> 3;
  int sw = (blockIdx.x & 7)*cpx + (blockIdx.x >> 3);
  const long m0 = (long)(sw % MT)*256;
  const long n0 = (long)(sw / MT)*256;

  const int prl0 = tid >> 3, q1 = 512 + tid, prl1 = q1 >> 3;
  const int sl0 = ((tid & 7) ^ (prl0 & 7)) * 8;
  const int sl1 = ((q1 & 7) ^ (prl1 & 7)) * 8;
  const int rowA0 = ((prl0 >> 6)*128) + (prl0 & 63);
  const int rowA1 = ((prl1 >> 6)*128) + (prl1 & 63);
  const int rowB0 = ((prl0 >> 5)*64) + (prl0 & 31);
  const int rowB1 = ((prl1 >> 5)*64) + (prl1 & 31);
  const ushort_t* aS0 = A + (m0 + rowA0)*K + sl0;
  const ushort_t* aS1 = A + (m0 + rowA1)*K + sl1;
  const ushort_t* bS0 = Bw + (n0 + rowB0)*K + sl0;
  const ushort_t* bS1 = Bw + (n0 + rowB1)*K + sl1;

  const int sw0 = (g ^ (c & 7)) * 8;
  const int sw1 = ((4 + g) ^ (c & 7)) * 8;
  const int aRowBase = wm*64 + c;
  const int bRowBase = wn*32 + c;

  f32x4 acc[8][4] = {};
  short8 af[4][2], bfr[2][2];
  const int NI = K >> 7;

  STAGE_A(0, 0, 0); STAGE_B(0, 0, 0);
  STAGE_A(0, 1, 0); STAGE_B(0, 1, 0);
  STAGE_A(1, 0, 1); STAGE_B(1, 0, 1);
  asm volatile("s_waitcnt vmcnt(4)" ::: "memory");
  __builtin_amdgcn_s_barrier();
  asm volatile("" ::: "memory");

  for (int j = 0; j < NI; ++j){
    const int t = 2*j;
    const bool more = (j + 1 < NI);
    PH(0, 0, 0, STAGE_A(1, 1, t+1), ((void)0));
    PH(0, 0, 1, STAGE_B(1, 1, t+1), ((void)0));
    PH(0, 1, 0, if(more){STAGE_A(0, 0, t+2);}, ((void)0));
    PH(0, 1, 1, if(more){STAGE_B(0, 0, t+2);}, WAITC(more));
    PH(1, 0, 0, if(more){STAGE_A(0, 1, t+2);}, ((void)0));
    PH(1, 0, 1, if(more){STAGE_B(0, 1, t+2);}, ((void)0));
    PH(1, 1, 0, if(more){STAGE_A(1, 0, t+3);}, ((void)0));
    PH(1, 1, 1, if(more){STAGE_B(1, 0, t+3);}, WAITC(more));
  }

  // epilogue: third 0/1 -> row-major Q/K; third 2 -> transposed V write
  const long rbase = m0 + wm*128 + g*4;
  const long cbase = n0 + wn*64 + c;
  const int third = (int)(n0 >> 11);          // uniform per block (256 | 2048)
  if (third < 2){
    ushort_t* dst = (third == 0) ? Cq : Ck;
    const long csub = cbase - (long)third*2048;
#pragma unroll
    for (int mi = 0; mi < 8; ++mi)
#pragma unroll
      for (int ni = 0; ni < 4; ++ni){
        long off = (rbase + mi*16)*2048 + csub + ni*16;
#pragma unroll
        for (int r = 0; r < 4; ++r)
          dst[off + (long)r*2048] = f2bf(acc[mi][ni][r]);
      }
  } else {
#pragma unroll
    for (int mi = 0; mi < 8; ++mi){
      const long row = rbase + mi*16;        // b*2048 + s (s 4-aligned)
      const long s = row & 2047, bb = row >> 11;
#pragma unroll
      for (int ni = 0; ni < 4; ++ni){
        long hd = cbase + ni*16 - 4096;
        long vaddr = ((bb*16 + (hd >> 7))*128 + (hd & 127))*2048 + s;
        ushort4 o4;
        o4.x = f2bf(acc[mi][ni][0]); o4.y = f2bf(acc[mi][ni][1]);
        o4.z = f2bf(acc[mi][ni][2]); o4.w = f2bf(acc[mi][ni][3]);
        *(ushort4*)&Vt[vaddr] = o4;
      }
    }
  }
}

// ---------------- m97-style NT GEMM (WO): C f32 ----------------
__global__ __launch_bounds__(256) void gemm_nt_lds(const ushort_t* __restrict__ A,
                                                   const ushort_t* __restrict__ B,
                                                   float* __restrict__ C,
                                                   int M, int N, int K){
  const int tid = threadIdx.x;
  const int l = tid & 63;
  const int g = l >> 4, c = l & 15;
  const int w = tid >> 6, wr = w >> 1, wc = w & 1;
  const long m0 = (long)blockIdx.x*128, n0 = (long)blockIdx.y*128;
  __shared__ ushort_t lds_a[128*32];
  __shared__ ushort_t lds_b[128*32];
  f32x4 acc[4][4] = {};
  const int q1 = tid, q2 = 256 + tid;
  const ushort_t* a1 = A + (m0 + (q1>>2))*(long)K + (q1&3)*8;
  const ushort_t* a2 = A + (m0 + (q2>>2))*(long)K + (q2&3)*8;
  const ushort_t* b1 = B + (n0 + (q1>>2))*(long)K + (q1&3)*8;
  const ushort_t* b2 = B + (n0 + (q2>>2))*(long)K + (q2&3)*8;
  for (int k0 = 0; k0 < K; k0 += 32){
    __syncthreads();
    gload_lds16(a1 + k0, &lds_a[q1*8]);
    gload_lds16(a2 + k0, &lds_a[q2*8]);
    gload_lds16(b1 + k0, &lds_b[q1*8]);
    gload_lds16(b2 + k0, &lds_b[q2*8]);
    __syncthreads();
    short8 af[4], bf[4];
#pragma unroll
    for (int i = 0; i < 4; ++i) af[i] = *(const short8*)&lds_a[(wr*64 + i*16 + c)*32 + g*8];
#pragma unroll
    for (int j = 0; j < 4; ++j) bf[j] = *(const short8*)&lds_b[(wc*64 + j*16 + c)*32 + g*8];
#pragma unroll
    for (int i = 0; i < 4; ++i)
#pragma unroll
      for (int j = 0; j < 4; ++j)
        acc[i][j] = __builtin_amdgcn_mfma_f32_16x16x32_bf16(af[i], bf[j], acc[i][j], 0, 0, 0);
  }
#pragma unroll
  for (int i = 0; i < 4; ++i)
#pragma unroll
    for (int j = 0; j < 4; ++j)
#pragma unroll
      for (int r = 0; r < 4; ++r)
        C[(m0 + wr*64 + i*16 + g*4 + r)*(long)N + n0 + wc*64 + j*16 + c] = acc[i][j][r];
}

// ---------------- flash attention (round-5 structure + defer-max) ----------------
__global__ __launch_bounds__(256) void attn_kernel(const ushort_t* __restrict__ Q,
                                                   const ushort_t* __restrict__ Kr,
                                                   const ushort_t* __restrict__ Vt,
                                                   ushort_t* __restrict__ O){
  const int tid = threadIdx.x;
  const int l = tid & 63, w = tid >> 6;
  const int g = l >> 4, c = l & 15;
  const int bh = blockIdx.x;
  const int qt = (int)gridDim.y - 1 - (int)blockIdx.y;
  const int b = bh >> 4, h = bh & 15;
  const int q0 = qt * 64;
  const int qw0 = q0 + w * 16;
  const int nt = qt + 1;

  __shared__ ushort_t k_lds[2][64*128];
  __shared__ ushort_t v_lds[2][128*64];
  __shared__ ushort_t p_lds[4][16*72];

  short8 qf[4];
  const long qbase = ((long)(b*2048 + qw0 + c))*2048 + h*128 + g*8;
#pragma unroll
  for (int ds = 0; ds < 4; ++ds) qf[ds] = *(const short8*)(Q + qbase + ds*32);

  const ushort_t* ksrc[4]; const ushort_t* vsrc[4];
  int kof[4], vof[4];
#pragma unroll
  for (int i = 0; i < 4; ++i){
    int q = i*256 + tid;
    int r = q >> 4, j = q & 15;
    ksrc[i] = Kr + ((long)(b*2048 + r))*2048 + h*128 + (j ^ (r & 7))*8;
    kof[i] = q*8;
    int d = q >> 3, jj = q & 7;
    vsrc[i] = Vt + ((long)(bh*128 + d))*2048 + (jj ^ (d & 7))*8;
    vof[i] = q*8;
  }

  f32x4 o[8] = {};
  float m = -1e30f, lsum = 0.f;
  const int sw = (c & 7) << 3;

#pragma unroll
  for (int i = 0; i < 4; ++i) gload_lds16(ksrc[i], &k_lds[0][kof[i]]);
#pragma unroll
  for (int i = 0; i < 4; ++i) gload_lds16(vsrc[i], &v_lds[0][vof[i]]);
  __syncthreads();

  for (int t = 0; t < nt; ++t){
    const int p = t & 1;
    if (t + 1 < nt){
#pragma unroll
      for (int i = 0; i < 4; ++i)
        gload_lds16(ksrc[i] + (long)(t+1)*64*2048, &k_lds[p^1][kof[i]]);
#pragma unroll
      for (int i = 0; i < 4; ++i)
        gload_lds16(vsrc[i] + (t+1)*64, &v_lds[p^1][vof[i]]);
    }
    const int kv0 = t*64;

    f32x4 s[4] = {};
    __builtin_amdgcn_s_setprio(1);
#pragma unroll
    for (int t4 = 0; t4 < 4; ++t4){
      const int row = 16*t4 + c;
#pragma unroll
      for (int ds = 0; ds < 4; ++ds){
        short8 kf = *(const short8*)&k_lds[p][(row*128 + ds*32 + g*8) ^ sw];
        s[t4] = __builtin_amdgcn_mfma_f32_16x16x32_bf16(kf, qf[ds], s[t4], 0, 0, 0);
      }
    }
    __builtin_amdgcn_s_setprio(0);
    if (kv0 + 63 > qw0){
      const int qg = qw0 + c;
#pragma unroll
      for (int t4 = 0; t4 < 4; ++t4)
#pragma unroll
        for (int r = 0; r < 4; ++r)
          if (kv0 + 16*t4 + 4*g + r > qg) s[t4][r] = -1e30f;
    }
    float tm = -1e30f;
#pragma unroll
    for (int t4 = 0; t4 < 4; ++t4)
      tm = fmaxf(tm, fmaxf(fmaxf(s[t4][0], s[t4][1]), fmaxf(s[t4][2], s[t4][3])));
    tm = fmaxf(tm, __shfl_xor(tm, 16, 64));
    tm = fmaxf(tm, __shfl_xor(tm, 32, 64));
    if (!__all(tm <= m + 8.f)){
      float mn = fmaxf(m, tm);
      float al = __expf(m - mn);
      m = mn;
      lsum *= al;
      float alr[4];
#pragma unroll
      for (int r = 0; r < 4; ++r) alr[r] = __shfl(al, 4*g + r, 64);
#pragma unroll
      for (int dt = 0; dt < 8; ++dt)
#pragma unroll
        for (int r = 0; r < 4; ++r) o[dt][r] *= alr[r];
    }
    float ps = 0.f;
#pragma unroll
    for (int t4 = 0; t4 < 4; ++t4)
#pragma unroll
      for (int r = 0; r < 4; ++r){ float pex = __expf(s[t4][r] - m); s[t4][r] = pex; ps += pex; }
    ps += __shfl_xor(ps, 16, 64);
    ps += __shfl_xor(ps, 32, 64);
    lsum += ps;
#pragma unroll
    for (int t4 = 0; t4 < 4; ++t4){
      uint2 pw;
      pw.x = (unsigned)f2bf(s[t4][0]) | ((unsigned)f2bf(s[t4][1]) << 16);
      pw.y = (unsigned)f2bf(s[t4][2]) | ((unsigned)f2bf(s[t4][3]) << 16);
      *reinterpret_cast<uint2*>(&p_lds[w][c*72 + 16*t4 + 4*g]) = pw;
    }
    __builtin_amdgcn_s_setprio(1);
#pragma unroll
    for (int kc = 0; kc < 2; ++kc){
      short8 pf = *(const short8*)&p_lds[w][c*72 + 32*kc + 8*g];
#pragma unroll
      for (int dt = 0; dt < 8; ++dt){
        short8 vf = *(const short8*)&v_lds[p][(((16*dt + c)*64) + kc*32 + g*8) ^ sw];
        o[dt] = __builtin_amdgcn_mfma_f32_16x16x32_bf16(pf, vf, o[dt], 0, 0, 0);
      }
    }
    __builtin_amdgcn_s_setprio(0);
    __syncthreads();
  }

  float inv = 1.f / lsum;
  float invr[4];
#pragma unroll
  for (int r = 0; r < 4; ++r) invr[r] = __shfl(inv, 4*g + r, 64);
  const long obase = ((long)(b*2048 + qw0 + g*4))*2048 + h*128 + c;
#pragma unroll
  for (int dt = 0; dt < 8; ++dt)
#pragma unroll
    for (int r = 0; r < 4; ++r)
      O[obase + (long)r*2048 + dt*16] = f2bf(o[dt][r] * invr[r]);
}

// ---------------- launcher ----------------
extern "C" void kernel_launch(void* const* d_in, const int* in_sizes, int n_in,
                              void* d_out, int out_size, void* d_ws, size_t ws_size,
                              hipStream_t stream){
  const float* x    = (const float*)d_in[0];
  const float* cosb = (const float*)d_in[1];
  const float* sinb = (const float*)d_in[2];
  const float* wq   = (const float*)d_in[3];
  const float* wk   = (const float*)d_in[4];
  const float* wv   = (const float*)d_in[5];
  const float* wo   = (const float*)d_in[6];
  float* out = (float*)d_out;

  const int S = 2048, DIM = 2048;
  const long MN = 4096;

  char* ws = (char*)d_ws;
  ushort_t* xb     = (ushort_t*)(ws);                 // 16MB
  ushort_t* wqkvb  = (ushort_t*)(ws + (16l<<20));     // 24MB
  ushort_t* wob    = (ushort_t*)(ws + (40l<<20));     // 8MB
  ushort_t* qstage = (ushort_t*)(ws + (48l<<20));     // 16MB
  ushort_t* kstage = (ushort_t*)(ws + (64l<<20));     // 16MB
  ushort_t* attnb  = (ushort_t*)(ws + (80l<<20));     // 16MB
  ushort_t* vt     = (ushort_t*)(ws + (96l<<20));     // 16MB -> 112MB total

  const long xn4 = MN*DIM/4, wn4 = (long)DIM*DIM/4;
  cast_bf16_kernel<<<(int)((xn4+255)/256), 256, 0, stream>>>(x, xb, xn4);
  cast4_bf16_kernel<<<dim3((int)((wn4+255)/256), 4), 256, 0, stream>>>(
      wq, wk, wv, wo,
      wqkvb, wqkvb + 4194304, wqkvb + 8388608, wob, wn4);

  // fused QKV projection (V written transposed into vt directly)
  gemm_qkv_8ph<<<(MN/256)*(6144/256), 512, 0, stream>>>(
      xb, wqkvb, qstage, kstage, vt, (int)(MN/256), DIM);

  const int ropeBlocks = (2*2048*16*16)/256;
  rope2_kernel<<<dim3(ropeBlocks, 2), 256, 0, stream>>>(qstage, kstage, cosb, sinb);
  attn_kernel<<<dim3(32, S/64), 256, 0, stream>>>(qstage, kstage, vt, attnb);
  gemm_nt_lds<<<dim3(MN/128, DIM/128), 256, 0, stream>>>(attnb, wob, out, (int)MN, DIM, DIM);
}